// Round 1
// baseline (21270.860 us; speedup 1.0000x reference)
//
#include <hip/hip_runtime.h>
#include <cmath>

#define T_LEN 2048
#define E_DIM 512
#define H_DIM 1024
#define G_DIM 4096   // 4*H
#define V_DIM 32000
#define LSTM_NB 256  // persistent blocks (1 per CU)

// ---------------------------------------------------------------------------
// Kernel T: transpose Wh (H x 4H) -> WhT (4H x H) so GEMV rows are contiguous.
// ---------------------------------------------------------------------------
__global__ __launch_bounds__(256) void trans_kernel(const float* __restrict__ Wh,
                                                    float* __restrict__ whT)
{
    __shared__ float tile[32][33];
    const int jb = blockIdx.x * 32;   // gate-col tile
    const int kb = blockIdx.y * 32;   // h-row tile
    const int tx = threadIdx.x & 31;
    const int ty = threadIdx.x >> 5;  // 0..7
    #pragma unroll
    for (int i = 0; i < 32; i += 8)
        tile[ty + i][tx] = Wh[(size_t)(kb + ty + i) * G_DIM + jb + tx];
    __syncthreads();
    #pragma unroll
    for (int i = 0; i < 32; i += 8)
        whT[(size_t)(jb + ty + i) * H_DIM + kb + tx] = tile[tx][ty + i];
}

// ---------------------------------------------------------------------------
// Kernel A: xg = gather(emb, sentence) @ Wi + bi + bh   (T x 4H)
// 64x64 tile, BK=16, 256 threads, 4x4 per thread, fp32.
// ---------------------------------------------------------------------------
__global__ __launch_bounds__(256) void xg_kernel(const int* __restrict__ sent,
                                                 const float* __restrict__ emb,
                                                 const float* __restrict__ Wi,
                                                 const float* __restrict__ bi,
                                                 const float* __restrict__ bh,
                                                 float* __restrict__ xg)
{
    __shared__ float As[16][68];  // k-major, padded
    __shared__ float Bs[16][68];
    const int tid = threadIdx.x;
    const int n0 = blockIdx.x * 64;
    const int m0 = blockIdx.y * 64;
    const int ty = tid >> 4, tx = tid & 15;
    const int rowA = tid >> 2;          // 0..63
    const int kcA  = (tid & 3) * 4;
    const int krB  = tid >> 4;          // 0..15
    const int cB   = (tid & 15) * 4;
    const int idA  = sent[m0 + rowA];

    float acc[4][4] = {};
    for (int k0 = 0; k0 < E_DIM; k0 += 16) {
        float4 a  = *reinterpret_cast<const float4*>(emb + (size_t)idA * E_DIM + k0 + kcA);
        float4 bv = *reinterpret_cast<const float4*>(Wi + (size_t)(k0 + krB) * G_DIM + n0 + cB);
        __syncthreads();
        As[kcA + 0][rowA] = a.x; As[kcA + 1][rowA] = a.y;
        As[kcA + 2][rowA] = a.z; As[kcA + 3][rowA] = a.w;
        *reinterpret_cast<float4*>(&Bs[krB][cB]) = bv;
        __syncthreads();
        #pragma unroll
        for (int kk = 0; kk < 16; ++kk) {
            float4 av = *reinterpret_cast<const float4*>(&As[kk][ty * 4]);
            float4 bw = *reinterpret_cast<const float4*>(&Bs[kk][tx * 4]);
            float aa[4] = {av.x, av.y, av.z, av.w};
            float bb[4] = {bw.x, bw.y, bw.z, bw.w};
            #pragma unroll
            for (int i = 0; i < 4; ++i)
                #pragma unroll
                for (int j = 0; j < 4; ++j)
                    acc[i][j] += aa[i] * bb[j];
        }
    }
    const int c = n0 + tx * 4;
    float4 biv = *reinterpret_cast<const float4*>(bi + c);
    float4 bhv = *reinterpret_cast<const float4*>(bh + c);
    #pragma unroll
    for (int i = 0; i < 4; ++i) {
        const int r = m0 + ty * 4 + i;
        float4 o;
        o.x = acc[i][0] + biv.x + bhv.x;
        o.y = acc[i][1] + biv.y + bhv.y;
        o.z = acc[i][2] + biv.z + bhv.z;
        o.w = acc[i][3] + biv.w + bhv.w;
        *reinterpret_cast<float4*>(xg + (size_t)r * G_DIM + c) = o;
    }
}

// ---------------------------------------------------------------------------
// Kernel B: persistent LSTM recurrence. 256 blocks x 256 threads.
// Block b owns h-indices s..s+3 (s = 4*b). Wave q computes the 4 dots of gate
// type q. Two-level monotonic grid barrier in ws (zeroed each launch).
// Cross-XCD h handoff via agent-scope atomics (bypass L1/L2 -> always fresh).
// ---------------------------------------------------------------------------
__global__ __launch_bounds__(256) void lstm_kernel(const float* __restrict__ xg,
                                                   const float* __restrict__ whT,
                                                   float* __restrict__ hs,
                                                   unsigned* __restrict__ sync,
                                                   int T)
{
    const int b    = blockIdx.x;
    const int tid  = threadIdx.x;
    const int wave = tid >> 6;
    const int lane = tid & 63;
    const int s    = b * 4;

    __shared__ float h_lds[H_DIM];
    __shared__ float c_lds[4];
    __shared__ float gate_lds[4][4];  // [gate_type][j]
    if (tid < 4) c_lds[tid] = 0.0f;

    for (int t = 0; t < T; ++t) {
        // stage h_{t-1}
        if (t == 0) {
            for (int i = tid; i < H_DIM; i += 256) h_lds[i] = 0.0f;
        } else {
            const float* hp = hs + (size_t)(t - 1) * H_DIM;
            #pragma unroll
            for (int r = 0; r < 4; ++r) {
                int i = r * 256 + tid;
                h_lds[i] = __hip_atomic_load(hp + i, __ATOMIC_RELAXED,
                                             __HIP_MEMORY_SCOPE_AGENT);
            }
        }
        __syncthreads();

        // wave `wave` computes 4 dot products: cols wave*H + s + j
        #pragma unroll
        for (int j = 0; j < 4; ++j) {
            const int col = wave * H_DIM + s + j;
            const float* wrow = whT + (size_t)col * H_DIM;
            float sum = 0.f;
            #pragma unroll
            for (int ch = 0; ch < 4; ++ch) {
                float4 w4 = *reinterpret_cast<const float4*>(wrow + ch * 256 + lane * 4);
                float4 h4 = *reinterpret_cast<const float4*>(&h_lds[ch * 256 + lane * 4]);
                sum += w4.x * h4.x + w4.y * h4.y + w4.z * h4.z + w4.w * h4.w;
            }
            #pragma unroll
            for (int off = 32; off; off >>= 1) sum += __shfl_xor(sum, off, 64);
            if (lane == 0)
                gate_lds[wave][j] = sum + xg[(size_t)t * G_DIM + col];
        }
        __syncthreads();

        if (tid < 4) {
            const int j = tid;
            float ig = gate_lds[0][j], fg = gate_lds[1][j];
            float gg = gate_lds[2][j], og = gate_lds[3][j];
            ig = 1.f / (1.f + expf(-ig));
            fg = 1.f / (1.f + expf(-fg));
            gg = tanhf(gg);
            og = 1.f / (1.f + expf(-og));
            float c = fg * c_lds[j] + ig * gg;
            c_lds[j] = c;
            float h = og * tanhf(c);
            __hip_atomic_store(hs + (size_t)t * H_DIM + s + j, h,
                               __ATOMIC_RELAXED, __HIP_MEMORY_SCOPE_AGENT);
        }
        __syncthreads();  // drains vmem (store visible) before the barrier bump

        if (tid == 0) {
            unsigned* grp = sync + 16 * (1 + (b >> 3));  // 32 groups of 8 blocks
            unsigned old = __hip_atomic_fetch_add(grp, 1u, __ATOMIC_RELEASE,
                                                  __HIP_MEMORY_SCOPE_AGENT);
            if ((old & 7u) == 7u) {
                __hip_atomic_fetch_add(sync, 1u, __ATOMIC_RELEASE,
                                       __HIP_MEMORY_SCOPE_AGENT);
            }
            const unsigned target = 32u * (unsigned)(t + 1);
            while (__hip_atomic_load(sync, __ATOMIC_RELAXED,
                                     __HIP_MEMORY_SCOPE_AGENT) < target) { }
        }
        __syncthreads();
    }
}

// ---------------------------------------------------------------------------
// Kernel C: logits = relu(hs @ fc_w^T + fc_b) written into d_out.
// 128x128 tile, BK=16, 256 threads, 8x8 per thread, fp32.
// ---------------------------------------------------------------------------
__global__ __launch_bounds__(256) void fc_kernel(const float* __restrict__ hs,
                                                 const float* __restrict__ fcw,
                                                 const float* __restrict__ fcb,
                                                 float* __restrict__ out)
{
    __shared__ float As[16][132];
    __shared__ float Bs[16][132];
    const int tid = threadIdx.x;
    const int n0 = blockIdx.x * 128;
    const int m0 = blockIdx.y * 128;
    const int ty = tid >> 4, tx = tid & 15;
    const int rL = tid >> 2;         // 0..63
    const int kL = (tid & 3) * 4;

    float acc[8][8] = {};
    for (int k0 = 0; k0 < H_DIM; k0 += 16) {
        float4 a0 = *reinterpret_cast<const float4*>(hs  + (size_t)(m0 + rL)      * H_DIM + k0 + kL);
        float4 a1 = *reinterpret_cast<const float4*>(hs  + (size_t)(m0 + rL + 64) * H_DIM + k0 + kL);
        float4 b0 = *reinterpret_cast<const float4*>(fcw + (size_t)(n0 + rL)      * H_DIM + k0 + kL);
        float4 b1 = *reinterpret_cast<const float4*>(fcw + (size_t)(n0 + rL + 64) * H_DIM + k0 + kL);
        __syncthreads();
        As[kL + 0][rL] = a0.x; As[kL + 1][rL] = a0.y; As[kL + 2][rL] = a0.z; As[kL + 3][rL] = a0.w;
        As[kL + 0][rL + 64] = a1.x; As[kL + 1][rL + 64] = a1.y; As[kL + 2][rL + 64] = a1.z; As[kL + 3][rL + 64] = a1.w;
        Bs[kL + 0][rL] = b0.x; Bs[kL + 1][rL] = b0.y; Bs[kL + 2][rL] = b0.z; Bs[kL + 3][rL] = b0.w;
        Bs[kL + 0][rL + 64] = b1.x; Bs[kL + 1][rL + 64] = b1.y; Bs[kL + 2][rL + 64] = b1.z; Bs[kL + 3][rL + 64] = b1.w;
        __syncthreads();
        #pragma unroll
        for (int kk = 0; kk < 16; ++kk) {
            float4 av0 = *reinterpret_cast<const float4*>(&As[kk][ty * 8]);
            float4 av1 = *reinterpret_cast<const float4*>(&As[kk][ty * 8 + 4]);
            float4 bv0 = *reinterpret_cast<const float4*>(&Bs[kk][tx * 8]);
            float4 bv1 = *reinterpret_cast<const float4*>(&Bs[kk][tx * 8 + 4]);
            float aa[8] = {av0.x, av0.y, av0.z, av0.w, av1.x, av1.y, av1.z, av1.w};
            float bb[8] = {bv0.x, bv0.y, bv0.z, bv0.w, bv1.x, bv1.y, bv1.z, bv1.w};
            #pragma unroll
            for (int i = 0; i < 8; ++i)
                #pragma unroll
                for (int j = 0; j < 8; ++j)
                    acc[i][j] += aa[i] * bb[j];
        }
    }
    const int c = n0 + tx * 8;
    float4 fb0 = *reinterpret_cast<const float4*>(fcb + c);
    float4 fb1 = *reinterpret_cast<const float4*>(fcb + c + 4);
    #pragma unroll
    for (int i = 0; i < 8; ++i) {
        const int r = m0 + ty * 8 + i;
        float4 o0, o1;
        o0.x = fmaxf(acc[i][0] + fb0.x, 0.f);
        o0.y = fmaxf(acc[i][1] + fb0.y, 0.f);
        o0.z = fmaxf(acc[i][2] + fb0.z, 0.f);
        o0.w = fmaxf(acc[i][3] + fb0.w, 0.f);
        o1.x = fmaxf(acc[i][4] + fb1.x, 0.f);
        o1.y = fmaxf(acc[i][5] + fb1.y, 0.f);
        o1.z = fmaxf(acc[i][6] + fb1.z, 0.f);
        o1.w = fmaxf(acc[i][7] + fb1.w, 0.f);
        *reinterpret_cast<float4*>(out + (size_t)r * V_DIM + c)     = o0;
        *reinterpret_cast<float4*>(out + (size_t)r * V_DIM + c + 4) = o1;
    }
}

// ---------------------------------------------------------------------------
// Kernel D: in-place row log-softmax on d_out (2048 rows x 32000).
// ---------------------------------------------------------------------------
__global__ __launch_bounds__(256) void lsm_kernel(float* __restrict__ out)
{
    const int row = blockIdx.x;
    float* p = out + (size_t)row * V_DIM;
    const int tid = threadIdx.x;
    __shared__ float red[256];

    float m = -1e30f;
    for (int i4 = tid; i4 < V_DIM / 4; i4 += 256) {
        float4 v = *reinterpret_cast<const float4*>(p + i4 * 4);
        m = fmaxf(m, fmaxf(fmaxf(v.x, v.y), fmaxf(v.z, v.w)));
    }
    red[tid] = m; __syncthreads();
    for (int sft = 128; sft; sft >>= 1) {
        if (tid < sft) red[tid] = fmaxf(red[tid], red[tid + sft]);
        __syncthreads();
    }
    m = red[0]; __syncthreads();

    float ssum = 0.f;
    for (int i4 = tid; i4 < V_DIM / 4; i4 += 256) {
        float4 v = *reinterpret_cast<const float4*>(p + i4 * 4);
        ssum += expf(v.x - m) + expf(v.y - m) + expf(v.z - m) + expf(v.w - m);
    }
    red[tid] = ssum; __syncthreads();
    for (int sft = 128; sft; sft >>= 1) {
        if (tid < sft) red[tid] += red[tid + sft];
        __syncthreads();
    }
    const float L = m + logf(red[0]);

    for (int i4 = tid; i4 < V_DIM / 4; i4 += 256) {
        float4 v = *reinterpret_cast<const float4*>(p + i4 * 4);
        v.x -= L; v.y -= L; v.z -= L; v.w -= L;
        *reinterpret_cast<float4*>(p + i4 * 4) = v;
    }
}

// ---------------------------------------------------------------------------
extern "C" void kernel_launch(void* const* d_in, const int* in_sizes, int n_in,
                              void* d_out, int out_size, void* d_ws, size_t ws_size,
                              hipStream_t stream)
{
    const int*   sent = (const int*)  d_in[0];
    const float* emb  = (const float*)d_in[1];
    const float* Wi   = (const float*)d_in[2];
    const float* Wh   = (const float*)d_in[3];
    const float* bi   = (const float*)d_in[4];
    const float* bh   = (const float*)d_in[5];
    const float* fcw  = (const float*)d_in[6];
    const float* fcb  = (const float*)d_in[7];
    float* out = (float*)d_out;

    uint8_t* ws = (uint8_t*)d_ws;
    unsigned* sync = (unsigned*)ws;                                   // 4 KiB
    float* hs  = (float*)(ws + 4096);                                 // T*H   = 8 MiB
    float* xg  = (float*)(ws + 4096 + (size_t)T_LEN * H_DIM * 4);     // T*4H  = 32 MiB
    float* whT = (float*)(ws + 4096 + (size_t)T_LEN * H_DIM * 4
                               + (size_t)T_LEN * G_DIM * 4);          // 4H*H  = 16 MiB

    hipMemsetAsync(sync, 0, 4096, stream);
    trans_kernel<<<dim3(G_DIM / 32, H_DIM / 32), 256, 0, stream>>>(Wh, whT);
    xg_kernel<<<dim3(G_DIM / 64, T_LEN / 64), 256, 0, stream>>>(sent, emb, Wi, bi, bh, xg);
    lstm_kernel<<<LSTM_NB, 256, 0, stream>>>(xg, whT, hs, sync, T_LEN);
    fc_kernel<<<dim3(V_DIM / 128, T_LEN / 128), 256, 0, stream>>>(hs, fcw, fcb, out);
    lsm_kernel<<<T_LEN, 256, 0, stream>>>(out);
}

// Round 2
// 14086.098 us; speedup vs baseline: 1.5101x; 1.5101x over previous
//
#include <hip/hip_runtime.h>
#include <hip/hip_bf16.h>
#include <cmath>

#define T_LEN 2048
#define E_DIM 512
#define H_DIM 1024
#define G_DIM 4096   // 4*H
#define V_DIM 32000
#define LSTM_NB 256  // persistent blocks (1 per CU)

typedef unsigned short ushortx8 __attribute__((ext_vector_type(8)));

__device__ __forceinline__ float bf2f(unsigned short u) {
    return __uint_as_float(((unsigned)u) << 16);
}

// ---------------------------------------------------------------------------
// Kernel P: WhT prep. Wh (H x 4H fp32) -> whTp (4H x H bf16), each row stored
// in a lane-permuted order so LSTM lane l reads 16 contiguous bf16 (32B):
//   source element i (= h index k): l=(i&255)>>2, e=i&3, c=i>>8
//   stored at pos = l*16 + c*4 + e.
// Grid 256 blocks x 256 thr; block handles 16 consecutive output rows (cols).
// Reads fully coalesced (16 cols x 4 k per wave-instr = 4 full 64B lines).
// ---------------------------------------------------------------------------
__global__ __launch_bounds__(256) void prep_kernel(const float* __restrict__ Wh,
                                                   unsigned short* __restrict__ whTp)
{
    const int c0  = blockIdx.x * 16;
    const int tid = threadIdx.x;
    const int cc  = tid & 15;   // col within group of 16
    const int kk  = tid >> 4;   // 0..15
    const int col = c0 + cc;
    unsigned short* dst = whTp + (size_t)col * H_DIM;
    #pragma unroll 4
    for (int r = 0; r < 64; ++r) {
        const int i = r * 16 + kk;                       // h index k
        float v = Wh[(size_t)i * G_DIM + col];
        const int pos = ((i & 255) >> 2) * 16 + (i >> 8) * 4 + (i & 3);
        __hip_bfloat16 b = __float2bfloat16(v);
        dst[pos] = *reinterpret_cast<unsigned short*>(&b);
    }
}

// ---------------------------------------------------------------------------
// Kernel A: xg = gather(emb, sentence) @ Wi + bi + bh   (T x 4H)  (unchanged)
// ---------------------------------------------------------------------------
__global__ __launch_bounds__(256) void xg_kernel(const int* __restrict__ sent,
                                                 const float* __restrict__ emb,
                                                 const float* __restrict__ Wi,
                                                 const float* __restrict__ bi,
                                                 const float* __restrict__ bh,
                                                 float* __restrict__ xg)
{
    __shared__ float As[16][68];
    __shared__ float Bs[16][68];
    const int tid = threadIdx.x;
    const int n0 = blockIdx.x * 64;
    const int m0 = blockIdx.y * 64;
    const int ty = tid >> 4, tx = tid & 15;
    const int rowA = tid >> 2;
    const int kcA  = (tid & 3) * 4;
    const int krB  = tid >> 4;
    const int cB   = (tid & 15) * 4;
    const int idA  = sent[m0 + rowA];

    float acc[4][4] = {};
    for (int k0 = 0; k0 < E_DIM; k0 += 16) {
        float4 a  = *reinterpret_cast<const float4*>(emb + (size_t)idA * E_DIM + k0 + kcA);
        float4 bv = *reinterpret_cast<const float4*>(Wi + (size_t)(k0 + krB) * G_DIM + n0 + cB);
        __syncthreads();
        As[kcA + 0][rowA] = a.x; As[kcA + 1][rowA] = a.y;
        As[kcA + 2][rowA] = a.z; As[kcA + 3][rowA] = a.w;
        *reinterpret_cast<float4*>(&Bs[krB][cB]) = bv;
        __syncthreads();
        #pragma unroll
        for (int kk = 0; kk < 16; ++kk) {
            float4 av = *reinterpret_cast<const float4*>(&As[kk][ty * 4]);
            float4 bw = *reinterpret_cast<const float4*>(&Bs[kk][tx * 4]);
            float aa[4] = {av.x, av.y, av.z, av.w};
            float bb[4] = {bw.x, bw.y, bw.z, bw.w};
            #pragma unroll
            for (int i = 0; i < 4; ++i)
                #pragma unroll
                for (int j = 0; j < 4; ++j)
                    acc[i][j] += aa[i] * bb[j];
        }
    }
    const int c = n0 + tx * 4;
    float4 biv = *reinterpret_cast<const float4*>(bi + c);
    float4 bhv = *reinterpret_cast<const float4*>(bh + c);
    #pragma unroll
    for (int i = 0; i < 4; ++i) {
        const int r = m0 + ty * 4 + i;
        float4 o;
        o.x = acc[i][0] + biv.x + bhv.x;
        o.y = acc[i][1] + biv.y + bhv.y;
        o.z = acc[i][2] + biv.z + bhv.z;
        o.w = acc[i][3] + biv.w + bhv.w;
        *reinterpret_cast<float4*>(xg + (size_t)r * G_DIM + c) = o;
    }
}

// ---------------------------------------------------------------------------
// Kernel B: persistent LSTM. 256 blocks x 256 threads, block b owns h-indices
// s..s+3 (16 gate dots; wave q does gate q). Sync = per-block epoch flags
// (flags[b] = completed steps), relaxed agent atomics only. bf16 L1-resident
// weights in permuted layout; h staged in LDS then registers.
// ---------------------------------------------------------------------------
__global__ __launch_bounds__(256) void lstm_kernel(const float* __restrict__ xg,
                                                   const unsigned short* __restrict__ whTp,
                                                   float* __restrict__ hs,
                                                   unsigned* __restrict__ flags,
                                                   int T)
{
    const int b    = blockIdx.x;
    const int tid  = threadIdx.x;
    const int wave = tid >> 6;
    const int lane = tid & 63;
    const int s    = b * 4;

    __shared__ float h_lds[H_DIM];
    __shared__ float gate_lds[4][4];
    __shared__ float xg_s[16];

    float c_val = 0.0f;   // meaningful for tid<4 only

    for (int t = 0; t < T; ++t) {
        // prefetch this step's 16 xg values (issues early, lands during poll)
        float xval = 0.f;
        if (tid < 16)
            xval = xg[(size_t)t * G_DIM + (tid >> 2) * H_DIM + s + (tid & 3)];

        // ---- wait for all producers of h_{t-1}: wave 0 polls 4 flags/lane
        if (t && wave == 0) {
            const unsigned tgt = (unsigned)t;
            const unsigned* fp = flags + lane * 4;
            unsigned m = 0;
            while (m != 15u) {
                #pragma unroll
                for (int q = 0; q < 4; ++q)
                    if (!((m >> q) & 1u) &&
                        __hip_atomic_load(fp + q, __ATOMIC_RELAXED,
                                          __HIP_MEMORY_SCOPE_AGENT) >= tgt)
                        m |= 1u << q;
            }
        }
        if (tid < 16) xg_s[tid] = xval;
        asm volatile("" ::: "memory");
        __syncthreads();

        // ---- stage h_{t-1} into LDS (agent atomics bypass stale L1/L2)
        if (t == 0) {
            #pragma unroll
            for (int r = 0; r < 4; ++r) h_lds[r * 256 + tid] = 0.0f;
        } else {
            const float* hp = hs + (size_t)(t - 1) * H_DIM;
            #pragma unroll
            for (int r = 0; r < 4; ++r)
                h_lds[r * 256 + tid] = __hip_atomic_load(hp + r * 256 + tid,
                                                         __ATOMIC_RELAXED,
                                                         __HIP_MEMORY_SCOPE_AGENT);
        }
        __syncthreads();

        // ---- h into registers (16 per lane, c-interleaved: elem c*256+4*lane+e)
        float hreg[16];
        #pragma unroll
        for (int c = 0; c < 4; ++c) {
            float4 hv = *reinterpret_cast<const float4*>(&h_lds[c * 256 + lane * 4]);
            hreg[c * 4 + 0] = hv.x; hreg[c * 4 + 1] = hv.y;
            hreg[c * 4 + 2] = hv.z; hreg[c * 4 + 3] = hv.w;
        }

        // ---- 4 dots per wave: row = wave*1024 + s + j, permuted bf16 layout
        #pragma unroll
        for (int j = 0; j < 4; ++j) {
            const ushortx8* wp = reinterpret_cast<const ushortx8*>(
                whTp + ((size_t)(wave << 10) + s + j) * H_DIM + lane * 16);
            ushortx8 w0 = wp[0];
            ushortx8 w1 = wp[1];
            float sum = 0.f;
            #pragma unroll
            for (int e = 0; e < 8; ++e) sum += bf2f(w0[e]) * hreg[e];
            #pragma unroll
            for (int e = 0; e < 8; ++e) sum += bf2f(w1[e]) * hreg[8 + e];
            #pragma unroll
            for (int off = 32; off; off >>= 1) sum += __shfl_xor(sum, off, 64);
            if (lane == 0) gate_lds[wave][j] = sum;
        }
        __syncthreads();

        // ---- gates + state update (4 threads), store h slice to L3
        if (tid < 4) {
            const int j = tid;
            float ig = gate_lds[0][j] + xg_s[j];
            float fg = gate_lds[1][j] + xg_s[4 + j];
            float gg = gate_lds[2][j] + xg_s[8 + j];
            float og = gate_lds[3][j] + xg_s[12 + j];
            ig = 1.f / (1.f + __expf(-ig));
            fg = 1.f / (1.f + __expf(-fg));
            gg = tanhf(gg);
            og = 1.f / (1.f + __expf(-og));
            c_val = fg * c_val + ig * gg;
            float h = og * tanhf(c_val);
            __hip_atomic_store(hs + (size_t)t * H_DIM + s + j, h,
                               __ATOMIC_RELAXED, __HIP_MEMORY_SCOPE_AGENT);
        }
        __syncthreads();   // drains vmcnt(0) -> h stores complete before flag

        if (tid == 0)
            __hip_atomic_store(flags + b, (unsigned)(t + 1),
                               __ATOMIC_RELAXED, __HIP_MEMORY_SCOPE_AGENT);
    }
}

// ---------------------------------------------------------------------------
// Kernel C: logits = relu(hs @ fc_w^T + fc_b) -> d_out   (unchanged)
// ---------------------------------------------------------------------------
__global__ __launch_bounds__(256) void fc_kernel(const float* __restrict__ hs,
                                                 const float* __restrict__ fcw,
                                                 const float* __restrict__ fcb,
                                                 float* __restrict__ out)
{
    __shared__ float As[16][132];
    __shared__ float Bs[16][132];
    const int tid = threadIdx.x;
    const int n0 = blockIdx.x * 128;
    const int m0 = blockIdx.y * 128;
    const int ty = tid >> 4, tx = tid & 15;
    const int rL = tid >> 2;
    const int kL = (tid & 3) * 4;

    float acc[8][8] = {};
    for (int k0 = 0; k0 < H_DIM; k0 += 16) {
        float4 a0 = *reinterpret_cast<const float4*>(hs  + (size_t)(m0 + rL)      * H_DIM + k0 + kL);
        float4 a1 = *reinterpret_cast<const float4*>(hs  + (size_t)(m0 + rL + 64) * H_DIM + k0 + kL);
        float4 b0 = *reinterpret_cast<const float4*>(fcw + (size_t)(n0 + rL)      * H_DIM + k0 + kL);
        float4 b1 = *reinterpret_cast<const float4*>(fcw + (size_t)(n0 + rL + 64) * H_DIM + k0 + kL);
        __syncthreads();
        As[kL + 0][rL] = a0.x; As[kL + 1][rL] = a0.y; As[kL + 2][rL] = a0.z; As[kL + 3][rL] = a0.w;
        As[kL + 0][rL + 64] = a1.x; As[kL + 1][rL + 64] = a1.y; As[kL + 2][rL + 64] = a1.z; As[kL + 3][rL + 64] = a1.w;
        Bs[kL + 0][rL] = b0.x; Bs[kL + 1][rL] = b0.y; Bs[kL + 2][rL] = b0.z; Bs[kL + 3][rL] = b0.w;
        Bs[kL + 0][rL + 64] = b1.x; Bs[kL + 1][rL + 64] = b1.y; Bs[kL + 2][rL + 64] = b1.z; Bs[kL + 3][rL + 64] = b1.w;
        __syncthreads();
        #pragma unroll
        for (int kk = 0; kk < 16; ++kk) {
            float4 av0 = *reinterpret_cast<const float4*>(&As[kk][ty * 8]);
            float4 av1 = *reinterpret_cast<const float4*>(&As[kk][ty * 8 + 4]);
            float4 bv0 = *reinterpret_cast<const float4*>(&Bs[kk][tx * 8]);
            float4 bv1 = *reinterpret_cast<const float4*>(&Bs[kk][tx * 8 + 4]);
            float aa[8] = {av0.x, av0.y, av0.z, av0.w, av1.x, av1.y, av1.z, av1.w};
            float bb[8] = {bv0.x, bv0.y, bv0.z, bv0.w, bv1.x, bv1.y, bv1.z, bv1.w};
            #pragma unroll
            for (int i = 0; i < 8; ++i)
                #pragma unroll
                for (int j = 0; j < 8; ++j)
                    acc[i][j] += aa[i] * bb[j];
        }
    }
    const int c = n0 + tx * 8;
    float4 fb0 = *reinterpret_cast<const float4*>(fcb + c);
    float4 fb1 = *reinterpret_cast<const float4*>(fcb + c + 4);
    #pragma unroll
    for (int i = 0; i < 8; ++i) {
        const int r = m0 + ty * 8 + i;
        float4 o0, o1;
        o0.x = fmaxf(acc[i][0] + fb0.x, 0.f);
        o0.y = fmaxf(acc[i][1] + fb0.y, 0.f);
        o0.z = fmaxf(acc[i][2] + fb0.z, 0.f);
        o0.w = fmaxf(acc[i][3] + fb0.w, 0.f);
        o1.x = fmaxf(acc[i][4] + fb1.x, 0.f);
        o1.y = fmaxf(acc[i][5] + fb1.y, 0.f);
        o1.z = fmaxf(acc[i][6] + fb1.z, 0.f);
        o1.w = fmaxf(acc[i][7] + fb1.w, 0.f);
        *reinterpret_cast<float4*>(out + (size_t)r * V_DIM + c)     = o0;
        *reinterpret_cast<float4*>(out + (size_t)r * V_DIM + c + 4) = o1;
    }
}

// ---------------------------------------------------------------------------
// Kernel D: in-place row log-softmax on d_out  (unchanged)
// ---------------------------------------------------------------------------
__global__ __launch_bounds__(256) void lsm_kernel(float* __restrict__ out)
{
    const int row = blockIdx.x;
    float* p = out + (size_t)row * V_DIM;
    const int tid = threadIdx.x;
    __shared__ float red[256];

    float m = -1e30f;
    for (int i4 = tid; i4 < V_DIM / 4; i4 += 256) {
        float4 v = *reinterpret_cast<const float4*>(p + i4 * 4);
        m = fmaxf(m, fmaxf(fmaxf(v.x, v.y), fmaxf(v.z, v.w)));
    }
    red[tid] = m; __syncthreads();
    for (int sft = 128; sft; sft >>= 1) {
        if (tid < sft) red[tid] = fmaxf(red[tid], red[tid + sft]);
        __syncthreads();
    }
    m = red[0]; __syncthreads();

    float ssum = 0.f;
    for (int i4 = tid; i4 < V_DIM / 4; i4 += 256) {
        float4 v = *reinterpret_cast<const float4*>(p + i4 * 4);
        ssum += expf(v.x - m) + expf(v.y - m) + expf(v.z - m) + expf(v.w - m);
    }
    red[tid] = ssum; __syncthreads();
    for (int sft = 128; sft; sft >>= 1) {
        if (tid < sft) red[tid] += red[tid + sft];
        __syncthreads();
    }
    const float L = m + logf(red[0]);

    for (int i4 = tid; i4 < V_DIM / 4; i4 += 256) {
        float4 v = *reinterpret_cast<const float4*>(p + i4 * 4);
        v.x -= L; v.y -= L; v.z -= L; v.w -= L;
        *reinterpret_cast<float4*>(p + i4 * 4) = v;
    }
}

// ---------------------------------------------------------------------------
extern "C" void kernel_launch(void* const* d_in, const int* in_sizes, int n_in,
                              void* d_out, int out_size, void* d_ws, size_t ws_size,
                              hipStream_t stream)
{
    const int*   sent = (const int*)  d_in[0];
    const float* emb  = (const float*)d_in[1];
    const float* Wi   = (const float*)d_in[2];
    const float* Wh   = (const float*)d_in[3];
    const float* bi   = (const float*)d_in[4];
    const float* bh   = (const float*)d_in[5];
    const float* fcw  = (const float*)d_in[6];
    const float* fcb  = (const float*)d_in[7];
    float* out = (float*)d_out;

    uint8_t* ws = (uint8_t*)d_ws;
    unsigned* flags = (unsigned*)ws;                                   // 4 KiB slot
    float* hs  = (float*)(ws + 4096);                                  // T*H  fp32 =  8 MiB
    float* xg  = (float*)(ws + 4096 + (size_t)T_LEN * H_DIM * 4);      // T*4H fp32 = 32 MiB
    unsigned short* whTp = (unsigned short*)(ws + 4096
                               + (size_t)T_LEN * H_DIM * 4
                               + (size_t)T_LEN * G_DIM * 4);           // 4H*H bf16 = 8 MiB

    hipMemsetAsync(flags, 0, 4096, stream);
    prep_kernel<<<G_DIM / 16, 256, 0, stream>>>(Wh, whTp);
    xg_kernel<<<dim3(G_DIM / 64, T_LEN / 64), 256, 0, stream>>>(sent, emb, Wi, bi, bh, xg);
    lstm_kernel<<<LSTM_NB, 256, 0, stream>>>(xg, whTp, hs, flags, T_LEN);
    fc_kernel<<<dim3(V_DIM / 128, T_LEN / 128), 256, 0, stream>>>(hs, fcw, fcb, out);
    lsm_kernel<<<T_LEN, 256, 0, stream>>>(out);
}

// Round 4
// 8791.998 us; speedup vs baseline: 2.4193x; 1.6021x over previous
//
#include <hip/hip_runtime.h>
#include <hip/hip_bf16.h>
#include <cmath>

#define T_LEN 2048
#define E_DIM 512
#define H_DIM 1024
#define G_DIM 4096   // 4*H
#define V_DIM 32000
#define LSTM_NB 256  // persistent blocks (1 per CU)

typedef unsigned short ushortx8 __attribute__((ext_vector_type(8)));
typedef unsigned short ushortx4 __attribute__((ext_vector_type(4)));
typedef unsigned long long ull;

__device__ __forceinline__ float bf2f(unsigned short u) {
    return __uint_as_float(((unsigned)u) << 16);
}
__device__ __forceinline__ unsigned short f2bf(float f) {
    __hip_bfloat16 b = __float2bfloat16(f);
    return *reinterpret_cast<unsigned short*>(&b);
}

// ---------------------------------------------------------------------------
// Kernel P: WhT prep. Wh (H x 4H fp32) -> whTp (4H x H bf16), each row stored
// lane-permuted so LSTM lane l reads 16 contiguous bf16 (32B):
//   source element i (h index): stored at pos = ((i&255)>>2)*16 + (i>>8)*4 + (i&3)
// ---------------------------------------------------------------------------
__global__ __launch_bounds__(256) void prep_kernel(const float* __restrict__ Wh,
                                                   unsigned short* __restrict__ whTp)
{
    const int c0  = blockIdx.x * 16;
    const int tid = threadIdx.x;
    const int cc  = tid & 15;
    const int kk  = tid >> 4;
    const int col = c0 + cc;
    unsigned short* dst = whTp + (size_t)col * H_DIM;
    #pragma unroll 4
    for (int r = 0; r < 64; ++r) {
        const int i = r * 16 + kk;
        float v = Wh[(size_t)i * G_DIM + col];
        const int pos = ((i & 255) >> 2) * 16 + (i >> 8) * 4 + (i & 3);
        dst[pos] = f2bf(v);
    }
}

// ---------------------------------------------------------------------------
// Kernel A: xg = gather(emb, sentence) @ Wi + bi + bh   (T x 4H), bf16 out.
// ---------------------------------------------------------------------------
__global__ __launch_bounds__(256) void xg_kernel(const int* __restrict__ sent,
                                                 const float* __restrict__ emb,
                                                 const float* __restrict__ Wi,
                                                 const float* __restrict__ bi,
                                                 const float* __restrict__ bh,
                                                 unsigned short* __restrict__ xg)
{
    __shared__ float As[16][68];
    __shared__ float Bs[16][68];
    const int tid = threadIdx.x;
    const int n0 = blockIdx.x * 64;
    const int m0 = blockIdx.y * 64;
    const int ty = tid >> 4, tx = tid & 15;
    const int rowA = tid >> 2;
    const int kcA  = (tid & 3) * 4;
    const int krB  = tid >> 4;
    const int cB   = (tid & 15) * 4;
    const int idA  = sent[m0 + rowA];

    float acc[4][4] = {};
    for (int k0 = 0; k0 < E_DIM; k0 += 16) {
        float4 a  = *reinterpret_cast<const float4*>(emb + (size_t)idA * E_DIM + k0 + kcA);
        float4 bv = *reinterpret_cast<const float4*>(Wi + (size_t)(k0 + krB) * G_DIM + n0 + cB);
        __syncthreads();
        As[kcA + 0][rowA] = a.x; As[kcA + 1][rowA] = a.y;
        As[kcA + 2][rowA] = a.z; As[kcA + 3][rowA] = a.w;
        *reinterpret_cast<float4*>(&Bs[krB][cB]) = bv;
        __syncthreads();
        #pragma unroll
        for (int kk = 0; kk < 16; ++kk) {
            float4 av = *reinterpret_cast<const float4*>(&As[kk][ty * 4]);
            float4 bw = *reinterpret_cast<const float4*>(&Bs[kk][tx * 4]);
            float aa[4] = {av.x, av.y, av.z, av.w};
            float bb[4] = {bw.x, bw.y, bw.z, bw.w};
            #pragma unroll
            for (int i = 0; i < 4; ++i)
                #pragma unroll
                for (int j = 0; j < 4; ++j)
                    acc[i][j] += aa[i] * bb[j];
        }
    }
    const int c = n0 + tx * 4;
    float4 biv = *reinterpret_cast<const float4*>(bi + c);
    float4 bhv = *reinterpret_cast<const float4*>(bh + c);
    #pragma unroll
    for (int i = 0; i < 4; ++i) {
        const int r = m0 + ty * 4 + i;
        ushortx4 o;
        o[0] = f2bf(acc[i][0] + biv.x + bhv.x);
        o[1] = f2bf(acc[i][1] + biv.y + bhv.y);
        o[2] = f2bf(acc[i][2] + biv.z + bhv.z);
        o[3] = f2bf(acc[i][3] + biv.w + bhv.w);
        *reinterpret_cast<ushortx4*>(xg + (size_t)r * G_DIM + c) = o;
    }
}

// ---------------------------------------------------------------------------
// Kernel B: persistent LSTM. 256 blocks x 256 threads, block b owns h-indices
// 4b..4b+3. h handoff: hpack[t][i] = {f32 h (lo), u32 tag=t+1 (hi)} written
// with ONE relaxed agent 8B atomic store — the store IS the signal, the poll
// load IS the data fetch. hpack memset to 0 each launch (stale tags impossible).
// Poll is BOUNDED (hang-safety): if the guard trips, results corrupt visibly
// instead of wedging the GPU.
// ---------------------------------------------------------------------------
__global__ __launch_bounds__(256) void lstm_kernel(const unsigned short* __restrict__ xg,
                                                   const unsigned short* __restrict__ whTp,
                                                   ull* __restrict__ hpack,
                                                   int T)
{
    const int b    = blockIdx.x;
    const int tid  = threadIdx.x;
    const int wave = tid >> 6;
    const int lane = tid & 63;
    const int s    = b * 4;

    __shared__ float h_lds[H_DIM];
    __shared__ float gate_lds[4][4];

    float c_val = 0.0f;   // meaningful for tid<4 only

    for (int t = 0; t < T; ++t) {
        // prefetch this step's xg values into REGISTERS of threads 0..3
        // (no shared staging -> no cross-step race)
        float xr[4] = {0.f, 0.f, 0.f, 0.f};
        if (tid < 4) {
            #pragma unroll
            for (int q = 0; q < 4; ++q)
                xr[q] = bf2f(xg[(size_t)t * G_DIM + q * H_DIM + s + tid]);
        }

        // ---- poll h_{t-1}: each thread owns 4 pairs (bounded spin)
        if (t) {
            const ull* pp = hpack + (size_t)(t - 1) * H_DIM + tid * 4;
            const unsigned tg = (unsigned)t;
            ull v0 = 0, v1 = 0, v2 = 0, v3 = 0;
            unsigned need = 15u;
            int guard = 0;
            while (need && ++guard < 16384) {
                if (need & 1u) {
                    v0 = __hip_atomic_load(pp + 0, __ATOMIC_RELAXED, __HIP_MEMORY_SCOPE_AGENT);
                    if ((unsigned)(v0 >> 32) == tg) need &= ~1u;
                }
                if (need & 2u) {
                    v1 = __hip_atomic_load(pp + 1, __ATOMIC_RELAXED, __HIP_MEMORY_SCOPE_AGENT);
                    if ((unsigned)(v1 >> 32) == tg) need &= ~2u;
                }
                if (need & 4u) {
                    v2 = __hip_atomic_load(pp + 2, __ATOMIC_RELAXED, __HIP_MEMORY_SCOPE_AGENT);
                    if ((unsigned)(v2 >> 32) == tg) need &= ~4u;
                }
                if (need & 8u) {
                    v3 = __hip_atomic_load(pp + 3, __ATOMIC_RELAXED, __HIP_MEMORY_SCOPE_AGENT);
                    if ((unsigned)(v3 >> 32) == tg) need &= ~8u;
                }
            }
            float4 hv;
            hv.x = __uint_as_float((unsigned)v0);
            hv.y = __uint_as_float((unsigned)v1);
            hv.z = __uint_as_float((unsigned)v2);
            hv.w = __uint_as_float((unsigned)v3);
            *reinterpret_cast<float4*>(&h_lds[tid * 4]) = hv;
        } else {
            *reinterpret_cast<float4*>(&h_lds[tid * 4]) = float4{0.f, 0.f, 0.f, 0.f};
        }
        __syncthreads();   // (1) h_lds staged

        // ---- h into registers (16/lane, c-interleaved)
        float hreg[16];
        #pragma unroll
        for (int c = 0; c < 4; ++c) {
            float4 hv = *reinterpret_cast<const float4*>(&h_lds[c * 256 + lane * 4]);
            hreg[c * 4 + 0] = hv.x; hreg[c * 4 + 1] = hv.y;
            hreg[c * 4 + 2] = hv.z; hreg[c * 4 + 3] = hv.w;
        }

        // ---- 4 dots per wave (row = wave*1024 + s + j), L1-resident bf16 wts
        #pragma unroll
        for (int j = 0; j < 4; ++j) {
            const ushortx8* wp = reinterpret_cast<const ushortx8*>(
                whTp + ((size_t)(wave << 10) + s + j) * H_DIM + lane * 16);
            ushortx8 w0 = wp[0];
            ushortx8 w1 = wp[1];
            float sum = 0.f;
            #pragma unroll
            for (int e = 0; e < 8; ++e) sum += bf2f(w0[e]) * hreg[e];
            #pragma unroll
            for (int e = 0; e < 8; ++e) sum += bf2f(w1[e]) * hreg[8 + e];
            #pragma unroll
            for (int off = 32; off; off >>= 1) sum += __shfl_xor(sum, off, 64);
            if (lane == 0) gate_lds[wave][j] = sum;
        }
        __syncthreads();   // (2) gates ready

        // ---- gates + state update (4 threads); single 8B store = data+signal
        if (tid < 4) {
            const int j = tid;
            float ig = gate_lds[0][j] + xr[0];
            float fg = gate_lds[1][j] + xr[1];
            float gg = gate_lds[2][j] + xr[2];
            float og = gate_lds[3][j] + xr[3];
            ig = 1.f / (1.f + __expf(-ig));
            fg = 1.f / (1.f + __expf(-fg));
            gg = tanhf(gg);
            og = 1.f / (1.f + __expf(-og));
            c_val = fg * c_val + ig * gg;
            float h = og * tanhf(c_val);
            ull pk = ((ull)(unsigned)(t + 1) << 32) | (ull)__float_as_uint(h);
            __hip_atomic_store(hpack + (size_t)t * H_DIM + s + j, pk,
                               __ATOMIC_RELAXED, __HIP_MEMORY_SCOPE_AGENT);
        }
        // no trailing barrier needed:
        //  - h_lds/gate_lds step-(t+1) writes occur only after barriers (2)/(1)
        //  - xg now staged in private registers
    }
}

// ---------------------------------------------------------------------------
// Kernel C: logits = relu(h @ fc_w^T + fc_b) -> d_out. A read from hpack
// pairs (h = even dwords). 128x128 tile, BK=16, 8x8/thread, fp32.
// ---------------------------------------------------------------------------
__global__ __launch_bounds__(256) void fc_kernel(const float* __restrict__ hp,  // pair array as floats
                                                 const float* __restrict__ fcw,
                                                 const float* __restrict__ fcb,
                                                 float* __restrict__ out)
{
    __shared__ float As[16][132];
    __shared__ float Bs[16][132];
    const int tid = threadIdx.x;
    const int n0 = blockIdx.x * 128;
    const int m0 = blockIdx.y * 128;
    const int ty = tid >> 4, tx = tid & 15;
    const int rL = tid >> 2;
    const int kL = (tid & 3) * 4;

    float acc[8][8] = {};
    for (int k0 = 0; k0 < H_DIM; k0 += 16) {
        const size_t ab0 = 2 * (((size_t)(m0 + rL)      << 10) + k0 + kL);
        const size_t ab1 = 2 * (((size_t)(m0 + rL + 64) << 10) + k0 + kL);
        float4 u00 = *reinterpret_cast<const float4*>(hp + ab0);
        float4 u01 = *reinterpret_cast<const float4*>(hp + ab0 + 4);
        float4 u10 = *reinterpret_cast<const float4*>(hp + ab1);
        float4 u11 = *reinterpret_cast<const float4*>(hp + ab1 + 4);
        float4 b0 = *reinterpret_cast<const float4*>(fcw + (size_t)(n0 + rL)      * H_DIM + k0 + kL);
        float4 b1 = *reinterpret_cast<const float4*>(fcw + (size_t)(n0 + rL + 64) * H_DIM + k0 + kL);
        __syncthreads();
        As[kL + 0][rL] = u00.x; As[kL + 1][rL] = u00.z; As[kL + 2][rL] = u01.x; As[kL + 3][rL] = u01.z;
        As[kL + 0][rL + 64] = u10.x; As[kL + 1][rL + 64] = u10.z; As[kL + 2][rL + 64] = u11.x; As[kL + 3][rL + 64] = u11.z;
        Bs[kL + 0][rL] = b0.x; Bs[kL + 1][rL] = b0.y; Bs[kL + 2][rL] = b0.z; Bs[kL + 3][rL] = b0.w;
        Bs[kL + 0][rL + 64] = b1.x; Bs[kL + 1][rL + 64] = b1.y; Bs[kL + 2][rL + 64] = b1.z; Bs[kL + 3][rL + 64] = b1.w;
        __syncthreads();
        #pragma unroll
        for (int kk = 0; kk < 16; ++kk) {
            float4 av0 = *reinterpret_cast<const float4*>(&As[kk][ty * 8]);
            float4 av1 = *reinterpret_cast<const float4*>(&As[kk][ty * 8 + 4]);
            float4 bv0 = *reinterpret_cast<const float4*>(&Bs[kk][tx * 8]);
            float4 bv1 = *reinterpret_cast<const float4*>(&Bs[kk][tx * 8 + 4]);
            float aa[8] = {av0.x, av0.y, av0.z, av0.w, av1.x, av1.y, av1.z, av1.w};
            float bb[8] = {bv0.x, bv0.y, bv0.z, bv0.w, bv1.x, bv1.y, bv1.z, bv1.w};
            #pragma unroll
            for (int i = 0; i < 8; ++i)
                #pragma unroll
                for (int j = 0; j < 8; ++j)
                    acc[i][j] += aa[i] * bb[j];
        }
    }
    const int c = n0 + tx * 8;
    float4 fb0 = *reinterpret_cast<const float4*>(fcb + c);
    float4 fb1 = *reinterpret_cast<const float4*>(fcb + c + 4);
    #pragma unroll
    for (int i = 0; i < 8; ++i) {
        const int r = m0 + ty * 8 + i;
        float4 o0, o1;
        o0.x = fmaxf(acc[i][0] + fb0.x, 0.f);
        o0.y = fmaxf(acc[i][1] + fb0.y, 0.f);
        o0.z = fmaxf(acc[i][2] + fb0.z, 0.f);
        o0.w = fmaxf(acc[i][3] + fb0.w, 0.f);
        o1.x = fmaxf(acc[i][4] + fb1.x, 0.f);
        o1.y = fmaxf(acc[i][5] + fb1.y, 0.f);
        o1.z = fmaxf(acc[i][6] + fb1.z, 0.f);
        o1.w = fmaxf(acc[i][7] + fb1.w, 0.f);
        *reinterpret_cast<float4*>(out + (size_t)r * V_DIM + c)     = o0;
        *reinterpret_cast<float4*>(out + (size_t)r * V_DIM + c + 4) = o1;
    }
}

// ---------------------------------------------------------------------------
// Kernel D: in-place row log-softmax on d_out.
// ---------------------------------------------------------------------------
__global__ __launch_bounds__(256) void lsm_kernel(float* __restrict__ out)
{
    const int row = blockIdx.x;
    float* p = out + (size_t)row * V_DIM;
    const int tid = threadIdx.x;
    __shared__ float red[256];

    float m = -1e30f;
    for (int i4 = tid; i4 < V_DIM / 4; i4 += 256) {
        float4 v = *reinterpret_cast<const float4*>(p + i4 * 4);
        m = fmaxf(m, fmaxf(fmaxf(v.x, v.y), fmaxf(v.z, v.w)));
    }
    red[tid] = m; __syncthreads();
    for (int sft = 128; sft; sft >>= 1) {
        if (tid < sft) red[tid] = fmaxf(red[tid], red[tid + sft]);
        __syncthreads();
    }
    m = red[0]; __syncthreads();

    float ssum = 0.f;
    for (int i4 = tid; i4 < V_DIM / 4; i4 += 256) {
        float4 v = *reinterpret_cast<const float4*>(p + i4 * 4);
        ssum += expf(v.x - m) + expf(v.y - m) + expf(v.z - m) + expf(v.w - m);
    }
    red[tid] = ssum; __syncthreads();
    for (int sft = 128; sft; sft >>= 1) {
        if (tid < sft) red[tid] += red[tid + sft];
        __syncthreads();
    }
    const float L = m + logf(red[0]);

    for (int i4 = tid; i4 < V_DIM / 4; i4 += 256) {
        float4 v = *reinterpret_cast<const float4*>(p + i4 * 4);
        v.x -= L; v.y -= L; v.z -= L; v.w -= L;
        *reinterpret_cast<float4*>(p + i4 * 4) = v;
    }
}

// ---------------------------------------------------------------------------
extern "C" void kernel_launch(void* const* d_in, const int* in_sizes, int n_in,
                              void* d_out, int out_size, void* d_ws, size_t ws_size,
                              hipStream_t stream)
{
    const int*   sent = (const int*)  d_in[0];
    const float* emb  = (const float*)d_in[1];
    const float* Wi   = (const float*)d_in[2];
    const float* Wh   = (const float*)d_in[3];
    const float* bi   = (const float*)d_in[4];
    const float* bh   = (const float*)d_in[5];
    const float* fcw  = (const float*)d_in[6];
    const float* fcb  = (const float*)d_in[7];
    float* out = (float*)d_out;

    uint8_t* ws = (uint8_t*)d_ws;
    ull* hpack = (ull*)ws;                                            // T*H*8  = 16 MiB
    unsigned short* xg = (unsigned short*)(ws + (size_t)T_LEN * H_DIM * 8);          // T*4H*2 = 16 MiB
    unsigned short* whTp = (unsigned short*)(ws + (size_t)T_LEN * H_DIM * 8
                                                + (size_t)T_LEN * G_DIM * 2);        // 4H*H*2 =  8 MiB

    hipMemsetAsync(hpack, 0, (size_t)T_LEN * H_DIM * 8, stream);
    prep_kernel<<<G_DIM / 16, 256, 0, stream>>>(Wh, whTp);
    xg_kernel<<<dim3(G_DIM / 64, T_LEN / 64), 256, 0, stream>>>(sent, emb, Wi, bi, bh, xg);
    lstm_kernel<<<LSTM_NB, 256, 0, stream>>>(xg, whTp, hpack, T_LEN);
    fc_kernel<<<dim3(V_DIM / 128, T_LEN / 128), 256, 0, stream>>>((const float*)hpack, fcw, fcb, out);
    lsm_kernel<<<T_LEN, 256, 0, stream>>>(out);
}

// Round 5
// 7434.592 us; speedup vs baseline: 2.8611x; 1.1826x over previous
//
#include <hip/hip_runtime.h>
#include <hip/hip_bf16.h>
#include <cmath>

#define T_LEN 2048
#define E_DIM 512
#define H_DIM 1024
#define G_DIM 4096   // 4*H
#define V_DIM 32000
#define LSTM_NB 256  // persistent blocks (1 per CU)

typedef unsigned short ushortx8 __attribute__((ext_vector_type(8)));
typedef unsigned short ushortx4 __attribute__((ext_vector_type(4)));
typedef short shortx8 __attribute__((ext_vector_type(8)));
typedef float floatx4 __attribute__((ext_vector_type(4)));
typedef unsigned long long ull;

__device__ __forceinline__ float bf2f(unsigned short u) {
    return __uint_as_float(((unsigned)u) << 16);
}
__device__ __forceinline__ unsigned short f2bf(float f) {
    __hip_bfloat16 b = __float2bfloat16(f);
    return *reinterpret_cast<unsigned short*>(&b);
}
__device__ __forceinline__ float fast_sigmoid(float x) {
    return 1.f / (1.f + __expf(-x));
}
__device__ __forceinline__ float fast_tanh(float x) {
    return 1.f - 2.f / (__expf(2.f * x) + 1.f);
}

// ---------------------------------------------------------------------------
// Kernel P: WhT prep. Wh (H x 4H fp32) -> whTp (4H x H bf16), lane-permuted:
//   source element i (h index): pos = ((i&255)>>2)*16 + (i>>8)*4 + (i&3)
// ---------------------------------------------------------------------------
__global__ __launch_bounds__(256) void prep_kernel(const float* __restrict__ Wh,
                                                   unsigned short* __restrict__ whTp)
{
    const int c0  = blockIdx.x * 16;
    const int tid = threadIdx.x;
    const int cc  = tid & 15;
    const int kk  = tid >> 4;
    const int col = c0 + cc;
    unsigned short* dst = whTp + (size_t)col * H_DIM;
    #pragma unroll 4
    for (int r = 0; r < 64; ++r) {
        const int i = r * 16 + kk;
        float v = Wh[(size_t)i * G_DIM + col];
        const int pos = ((i & 255) >> 2) * 16 + (i >> 8) * 4 + (i & 3);
        dst[pos] = f2bf(v);
    }
}

// ---------------------------------------------------------------------------
// Kernel F: fc_w (V x H fp32) -> bf16 copy. 8 elems/thread.
// ---------------------------------------------------------------------------
__global__ __launch_bounds__(256) void fcwconv_kernel(const float* __restrict__ src,
                                                      unsigned short* __restrict__ dst)
{
    const size_t i = ((size_t)blockIdx.x * 256 + threadIdx.x) * 8;
    float4 a = *reinterpret_cast<const float4*>(src + i);
    float4 b = *reinterpret_cast<const float4*>(src + i + 4);
    ushortx8 o;
    o[0] = f2bf(a.x); o[1] = f2bf(a.y); o[2] = f2bf(a.z); o[3] = f2bf(a.w);
    o[4] = f2bf(b.x); o[5] = f2bf(b.y); o[6] = f2bf(b.z); o[7] = f2bf(b.w);
    *reinterpret_cast<ushortx8*>(dst + i) = o;
}

// ---------------------------------------------------------------------------
// Kernel H: hpack pairs {f32 h, u32 tag} -> hb bf16 (T x H). 4 pairs/thread.
// ---------------------------------------------------------------------------
__global__ __launch_bounds__(256) void hconv_kernel(const ull* __restrict__ hpack,
                                                    unsigned short* __restrict__ hb)
{
    const size_t i = ((size_t)blockIdx.x * 256 + threadIdx.x) * 4;
    ushortx4 o;
    #pragma unroll
    for (int q = 0; q < 4; ++q)
        o[q] = f2bf(__uint_as_float((unsigned)hpack[i + q]));
    *reinterpret_cast<ushortx4*>(hb + i) = o;
}

// ---------------------------------------------------------------------------
// Kernel A: xg = gather(emb, sentence) @ Wi + bi + bh   (T x 4H), bf16 out.
// ---------------------------------------------------------------------------
__global__ __launch_bounds__(256) void xg_kernel(const int* __restrict__ sent,
                                                 const float* __restrict__ emb,
                                                 const float* __restrict__ Wi,
                                                 const float* __restrict__ bi,
                                                 const float* __restrict__ bh,
                                                 unsigned short* __restrict__ xg)
{
    __shared__ float As[16][68];
    __shared__ float Bs[16][68];
    const int tid = threadIdx.x;
    const int n0 = blockIdx.x * 64;
    const int m0 = blockIdx.y * 64;
    const int ty = tid >> 4, tx = tid & 15;
    const int rowA = tid >> 2;
    const int kcA  = (tid & 3) * 4;
    const int krB  = tid >> 4;
    const int cB   = (tid & 15) * 4;
    const int idA  = sent[m0 + rowA];

    float acc[4][4] = {};
    for (int k0 = 0; k0 < E_DIM; k0 += 16) {
        float4 a  = *reinterpret_cast<const float4*>(emb + (size_t)idA * E_DIM + k0 + kcA);
        float4 bv = *reinterpret_cast<const float4*>(Wi + (size_t)(k0 + krB) * G_DIM + n0 + cB);
        __syncthreads();
        As[kcA + 0][rowA] = a.x; As[kcA + 1][rowA] = a.y;
        As[kcA + 2][rowA] = a.z; As[kcA + 3][rowA] = a.w;
        *reinterpret_cast<float4*>(&Bs[krB][cB]) = bv;
        __syncthreads();
        #pragma unroll
        for (int kk = 0; kk < 16; ++kk) {
            float4 av = *reinterpret_cast<const float4*>(&As[kk][ty * 4]);
            float4 bw = *reinterpret_cast<const float4*>(&Bs[kk][tx * 4]);
            float aa[4] = {av.x, av.y, av.z, av.w};
            float bb[4] = {bw.x, bw.y, bw.z, bw.w};
            #pragma unroll
            for (int i = 0; i < 4; ++i)
                #pragma unroll
                for (int j = 0; j < 4; ++j)
                    acc[i][j] += aa[i] * bb[j];
        }
    }
    const int c = n0 + tx * 4;
    float4 biv = *reinterpret_cast<const float4*>(bi + c);
    float4 bhv = *reinterpret_cast<const float4*>(bh + c);
    #pragma unroll
    for (int i = 0; i < 4; ++i) {
        const int r = m0 + ty * 4 + i;
        ushortx4 o;
        o[0] = f2bf(acc[i][0] + biv.x + bhv.x);
        o[1] = f2bf(acc[i][1] + biv.y + bhv.y);
        o[2] = f2bf(acc[i][2] + biv.z + bhv.z);
        o[3] = f2bf(acc[i][3] + biv.w + bhv.w);
        *reinterpret_cast<ushortx4*>(xg + (size_t)r * G_DIM + c) = o;
    }
}

// ---------------------------------------------------------------------------
// Kernel B: persistent LSTM. 256 blocks x 256 threads, block b owns h-indices
// 4b..4b+3. h handoff: hpack[t][i] = {f32 h (lo), u32 tag=t+1 (hi)}, one
// relaxed agent 8B atomic store = data+signal. Poll issues all 4 loads
// UNCONDITIONALLY per sweep (one waitcnt, one combined check) -> 1 RT/sweep.
// Bounded spin for hang-safety. hpack memset to 0 each launch.
// ---------------------------------------------------------------------------
__global__ __launch_bounds__(256) void lstm_kernel(const unsigned short* __restrict__ xg,
                                                   const unsigned short* __restrict__ whTp,
                                                   ull* __restrict__ hpack,
                                                   int T)
{
    const int b    = blockIdx.x;
    const int tid  = threadIdx.x;
    const int wave = tid >> 6;
    const int lane = tid & 63;
    const int s    = b * 4;

    __shared__ float h_lds[H_DIM];
    __shared__ float gate_lds[4][4];

    float c_val = 0.0f;   // meaningful for tid<4 only

    for (int t = 0; t < T; ++t) {
        // prefetch this step's xg values into registers of threads 0..3
        float xr[4] = {0.f, 0.f, 0.f, 0.f};
        if (tid < 4) {
            #pragma unroll
            for (int q = 0; q < 4; ++q)
                xr[q] = bf2f(xg[(size_t)t * G_DIM + q * H_DIM + s + tid]);
        }

        // ---- poll h_{t-1}: 4 pairs/thread, batched loads, bounded spin
        if (t) {
            const ull* pp = hpack + (size_t)(t - 1) * H_DIM + tid * 4;
            const unsigned tg = (unsigned)t;
            ull v0, v1, v2, v3;
            int guard = 0;
            bool ok;
            do {
                v0 = __hip_atomic_load(pp + 0, __ATOMIC_RELAXED, __HIP_MEMORY_SCOPE_AGENT);
                v1 = __hip_atomic_load(pp + 1, __ATOMIC_RELAXED, __HIP_MEMORY_SCOPE_AGENT);
                v2 = __hip_atomic_load(pp + 2, __ATOMIC_RELAXED, __HIP_MEMORY_SCOPE_AGENT);
                v3 = __hip_atomic_load(pp + 3, __ATOMIC_RELAXED, __HIP_MEMORY_SCOPE_AGENT);
                ok = (((unsigned)(v0 >> 32)) == tg) & (((unsigned)(v1 >> 32)) == tg)
                   & (((unsigned)(v2 >> 32)) == tg) & (((unsigned)(v3 >> 32)) == tg);
            } while (!ok && ++guard < 32768);
            float4 hv;
            hv.x = __uint_as_float((unsigned)v0);
            hv.y = __uint_as_float((unsigned)v1);
            hv.z = __uint_as_float((unsigned)v2);
            hv.w = __uint_as_float((unsigned)v3);
            *reinterpret_cast<float4*>(&h_lds[tid * 4]) = hv;
        } else {
            *reinterpret_cast<float4*>(&h_lds[tid * 4]) = float4{0.f, 0.f, 0.f, 0.f};
        }
        __syncthreads();   // (1) h_lds staged

        // ---- h into registers (16/lane, c-interleaved)
        float hreg[16];
        #pragma unroll
        for (int c = 0; c < 4; ++c) {
            float4 hv = *reinterpret_cast<const float4*>(&h_lds[c * 256 + lane * 4]);
            hreg[c * 4 + 0] = hv.x; hreg[c * 4 + 1] = hv.y;
            hreg[c * 4 + 2] = hv.z; hreg[c * 4 + 3] = hv.w;
        }

        // ---- 4 dots per wave (row = wave*1024 + s + j), L1-resident bf16 wts
        #pragma unroll
        for (int j = 0; j < 4; ++j) {
            const ushortx8* wp = reinterpret_cast<const ushortx8*>(
                whTp + ((size_t)(wave << 10) + s + j) * H_DIM + lane * 16);
            ushortx8 w0 = wp[0];
            ushortx8 w1 = wp[1];
            float sum = 0.f;
            #pragma unroll
            for (int e = 0; e < 8; ++e) sum += bf2f(w0[e]) * hreg[e];
            #pragma unroll
            for (int e = 0; e < 8; ++e) sum += bf2f(w1[e]) * hreg[8 + e];
            #pragma unroll
            for (int off = 32; off; off >>= 1) sum += __shfl_xor(sum, off, 64);
            if (lane == 0) gate_lds[wave][j] = sum;
        }
        __syncthreads();   // (2) gates ready

        // ---- gates + state update (4 threads); single 8B store = data+signal
        if (tid < 4) {
            const int j = tid;
            float ig = fast_sigmoid(gate_lds[0][j] + xr[0]);
            float fg = fast_sigmoid(gate_lds[1][j] + xr[1]);
            float gg = fast_tanh(gate_lds[2][j] + xr[2]);
            float og = fast_sigmoid(gate_lds[3][j] + xr[3]);
            c_val = fg * c_val + ig * gg;
            float h = og * fast_tanh(c_val);
            ull pk = ((ull)(unsigned)(t + 1) << 32) | (ull)__float_as_uint(h);
            __hip_atomic_store(hpack + (size_t)t * H_DIM + s + j, pk,
                               __ATOMIC_RELAXED, __HIP_MEMORY_SCOPE_AGENT);
        }
        // no trailing barrier needed (xg in regs; LDS rewrites fenced by (1)/(2))
    }
}

// ---------------------------------------------------------------------------
// Kernel C: logits = relu(hb @ fcwb^T + fc_b) -> d_out via bf16 MFMA.
// Block: 256 thr (4 waves), tile 128(M) x 64(N); wave w owns rows w*32..+32.
// mfma_f32_16x16x32_bf16; A/B frag: lane l holds 8 K-contig elems of
// row/col (l&15) at k-offset (l>>4)*8. C/D: col=lane&15, row=(lane>>4)*4+reg.
// ---------------------------------------------------------------------------
__global__ __launch_bounds__(256) void fc_kernel(const unsigned short* __restrict__ hb,
                                                 const unsigned short* __restrict__ fcwb,
                                                 const float* __restrict__ fcb,
                                                 float* __restrict__ out)
{
    const int tid  = threadIdx.x;
    const int w    = tid >> 6;
    const int lane = tid & 63;
    const int n0 = blockIdx.x * 64;
    const int m0 = blockIdx.y * 128;
    const int lrow = lane & 15;
    const int lk   = (lane >> 4) * 8;

    floatx4 acc[2][4] = {};
    const unsigned short* a0p = hb + (size_t)(m0 + w * 32 + lrow) * H_DIM + lk;
    const unsigned short* a1p = a0p + 16 * H_DIM;
    const unsigned short* b0p = fcwb + (size_t)(n0 + lrow) * H_DIM + lk;

    for (int k0 = 0; k0 < H_DIM; k0 += 32) {
        shortx8 a0 = *reinterpret_cast<const shortx8*>(a0p + k0);
        shortx8 a1 = *reinterpret_cast<const shortx8*>(a1p + k0);
        shortx8 b0 = *reinterpret_cast<const shortx8*>(b0p + k0);
        shortx8 b1 = *reinterpret_cast<const shortx8*>(b0p + 16 * H_DIM + k0);
        shortx8 b2 = *reinterpret_cast<const shortx8*>(b0p + 32 * H_DIM + k0);
        shortx8 b3 = *reinterpret_cast<const shortx8*>(b0p + 48 * H_DIM + k0);
        acc[0][0] = __builtin_amdgcn_mfma_f32_16x16x32_bf16(a0, b0, acc[0][0], 0, 0, 0);
        acc[0][1] = __builtin_amdgcn_mfma_f32_16x16x32_bf16(a0, b1, acc[0][1], 0, 0, 0);
        acc[0][2] = __builtin_amdgcn_mfma_f32_16x16x32_bf16(a0, b2, acc[0][2], 0, 0, 0);
        acc[0][3] = __builtin_amdgcn_mfma_f32_16x16x32_bf16(a0, b3, acc[0][3], 0, 0, 0);
        acc[1][0] = __builtin_amdgcn_mfma_f32_16x16x32_bf16(a1, b0, acc[1][0], 0, 0, 0);
        acc[1][1] = __builtin_amdgcn_mfma_f32_16x16x32_bf16(a1, b1, acc[1][1], 0, 0, 0);
        acc[1][2] = __builtin_amdgcn_mfma_f32_16x16x32_bf16(a1, b2, acc[1][2], 0, 0, 0);
        acc[1][3] = __builtin_amdgcn_mfma_f32_16x16x32_bf16(a1, b3, acc[1][3], 0, 0, 0);
    }

    #pragma unroll
    for (int j = 0; j < 4; ++j) {
        const int c = n0 + j * 16 + lrow;
        const float bias = fcb[c];
        #pragma unroll
        for (int i = 0; i < 2; ++i) {
            #pragma unroll
            for (int reg = 0; reg < 4; ++reg) {
                const int r = m0 + w * 32 + i * 16 + (lane >> 4) * 4 + reg;
                out[(size_t)r * V_DIM + c] = fmaxf(acc[i][j][reg] + bias, 0.f);
            }
        }
    }
}

// ---------------------------------------------------------------------------
// Kernel D: in-place row log-softmax on d_out. Online max/sum (2 passes).
// ---------------------------------------------------------------------------
__global__ __launch_bounds__(256) void lsm_kernel(float* __restrict__ out)
{
    const int row = blockIdx.x;
    float* p = out + (size_t)row * V_DIM;
    const int tid = threadIdx.x;
    __shared__ float ms[256], ss[256];

    float m = -1e30f, sacc = 0.f;
    for (int i4 = tid; i4 < V_DIM / 4; i4 += 256) {
        float4 v = *reinterpret_cast<const float4*>(p + i4 * 4);
        float vm = fmaxf(fmaxf(v.x, v.y), fmaxf(v.z, v.w));
        if (vm > m) { sacc *= __expf(m - vm); m = vm; }
        sacc += __expf(v.x - m) + __expf(v.y - m) + __expf(v.z - m) + __expf(v.w - m);
    }
    ms[tid] = m; ss[tid] = sacc; __syncthreads();
    for (int sft = 128; sft; sft >>= 1) {
        if (tid < sft) {
            float m2 = ms[tid + sft], s2 = ss[tid + sft];
            float mm = fmaxf(ms[tid], m2);
            ss[tid] = ss[tid] * __expf(ms[tid] - mm) + s2 * __expf(m2 - mm);
            ms[tid] = mm;
        }
        __syncthreads();
    }
    const float L = ms[0] + logf(ss[0]);

    for (int i4 = tid; i4 < V_DIM / 4; i4 += 256) {
        float4 v = *reinterpret_cast<const float4*>(p + i4 * 4);
        v.x -= L; v.y -= L; v.z -= L; v.w -= L;
        *reinterpret_cast<float4*>(p + i4 * 4) = v;
    }
}

// ---------------------------------------------------------------------------
extern "C" void kernel_launch(void* const* d_in, const int* in_sizes, int n_in,
                              void* d_out, int out_size, void* d_ws, size_t ws_size,
                              hipStream_t stream)
{
    const int*   sent = (const int*)  d_in[0];
    const float* emb  = (const float*)d_in[1];
    const float* Wi   = (const float*)d_in[2];
    const float* Wh   = (const float*)d_in[3];
    const float* bi   = (const float*)d_in[4];
    const float* bh   = (const float*)d_in[5];
    const float* fcw  = (const float*)d_in[6];
    const float* fcb  = (const float*)d_in[7];
    float* out = (float*)d_out;

    uint8_t* ws = (uint8_t*)d_ws;
    size_t off = 0;
    ull* hpack = (ull*)(ws + off);            off += (size_t)T_LEN * H_DIM * 8;   // 16 MiB
    unsigned short* xg   = (unsigned short*)(ws + off); off += (size_t)T_LEN * G_DIM * 2;  // 16 MiB
    unsigned short* whTp = (unsigned short*)(ws + off); off += (size_t)G_DIM * H_DIM * 2;  //  8 MiB
    unsigned short* fcwb = (unsigned short*)(ws + off); off += (size_t)V_DIM * H_DIM * 2;  // 62.5 MiB
    unsigned short* hb   = (unsigned short*)(ws + off); off += (size_t)T_LEN * H_DIM * 2;  //  4 MiB

    hipMemsetAsync(hpack, 0, (size_t)T_LEN * H_DIM * 8, stream);
    prep_kernel<<<G_DIM / 16, 256, 0, stream>>>(Wh, whTp);
    fcwconv_kernel<<<(int)(((size_t)V_DIM * H_DIM / 8) / 256), 256, 0, stream>>>(fcw, fcwb);
    xg_kernel<<<dim3(G_DIM / 64, T_LEN / 64), 256, 0, stream>>>(sent, emb, Wi, bi, bh, xg);
    lstm_kernel<<<LSTM_NB, 256, 0, stream>>>(xg, whTp, hpack, T_LEN);
    hconv_kernel<<<(int)(((size_t)T_LEN * H_DIM / 4) / 256), 256, 0, stream>>>(hpack, hb);
    fc_kernel<<<dim3(V_DIM / 64, T_LEN / 128), 256, 0, stream>>>(hb, fcwb, fcb, out);
    lsm_kernel<<<T_LEN, 256, 0, stream>>>(out);
}

// Round 6
// 5795.378 us; speedup vs baseline: 3.6703x; 1.2828x over previous
//
#include <hip/hip_runtime.h>
#include <hip/hip_bf16.h>
#include <cmath>

#define T_LEN 2048
#define E_DIM 512
#define H_DIM 1024
#define G_DIM 4096   // 4*H
#define V_DIM 32000
#define LSTM_NB 256  // persistent blocks (1 per CU)

typedef unsigned short ushortx8 __attribute__((ext_vector_type(8)));
typedef unsigned short ushortx4 __attribute__((ext_vector_type(4)));
typedef short shortx8 __attribute__((ext_vector_type(8)));
typedef float floatx4 __attribute__((ext_vector_type(4)));
typedef unsigned uintx4 __attribute__((ext_vector_type(4)));

__device__ __forceinline__ float bf2f(unsigned short u) {
    return __uint_as_float(((unsigned)u) << 16);
}
__device__ __forceinline__ unsigned short f2bf(float f) {
    __hip_bfloat16 b = __float2bfloat16(f);
    return *reinterpret_cast<unsigned short*>(&b);
}
__device__ __forceinline__ float fast_sigmoid(float x) {
    return 1.f / (1.f + __expf(-x));
}
__device__ __forceinline__ float fast_tanh(float x) {
    return 1.f - 2.f / (__expf(2.f * x) + 1.f);
}

// ---------------------------------------------------------------------------
// Kernel P: Wh (H x 4H fp32) -> whTp (4H x H bf16), lane-permuted per row:
//   source h-index i stored at pos = ((i&255)>>2)*16 + (i>>8)*4 + (i&3)
// ---------------------------------------------------------------------------
__global__ __launch_bounds__(256) void prep_kernel(const float* __restrict__ Wh,
                                                   unsigned short* __restrict__ whTp)
{
    const int c0  = blockIdx.x * 16;
    const int tid = threadIdx.x;
    const int cc  = tid & 15;
    const int kk  = tid >> 4;
    const int col = c0 + cc;
    unsigned short* dst = whTp + (size_t)col * H_DIM;
    #pragma unroll 4
    for (int r = 0; r < 64; ++r) {
        const int i = r * 16 + kk;
        float v = Wh[(size_t)i * G_DIM + col];
        const int pos = ((i & 255) >> 2) * 16 + (i >> 8) * 4 + (i & 3);
        dst[pos] = f2bf(v);
    }
}

// ---------------------------------------------------------------------------
// Kernel E: emb (V x E fp32) -> bf16 copy.
// ---------------------------------------------------------------------------
__global__ __launch_bounds__(256) void embconv_kernel(const float* __restrict__ src,
                                                      unsigned short* __restrict__ dst)
{
    const size_t i = ((size_t)blockIdx.x * 256 + threadIdx.x) * 8;
    float4 a = *reinterpret_cast<const float4*>(src + i);
    float4 b = *reinterpret_cast<const float4*>(src + i + 4);
    ushortx8 o;
    o[0] = f2bf(a.x); o[1] = f2bf(a.y); o[2] = f2bf(a.z); o[3] = f2bf(a.w);
    o[4] = f2bf(b.x); o[5] = f2bf(b.y); o[6] = f2bf(b.z); o[7] = f2bf(b.w);
    *reinterpret_cast<ushortx8*>(dst + i) = o;
}

// ---------------------------------------------------------------------------
// Kernel W: Wi (E x 4H fp32) -> wiT (4H x E bf16) transpose+convert.
// ---------------------------------------------------------------------------
__global__ __launch_bounds__(256) void wiconv_kernel(const float* __restrict__ Wi,
                                                     unsigned short* __restrict__ wiT)
{
    __shared__ float tile[32][33];
    const int nb = blockIdx.x * 32;
    const int kb = blockIdx.y * 32;
    const int tx = threadIdx.x & 31;
    const int ty = threadIdx.x >> 5;  // 0..7
    #pragma unroll
    for (int i = 0; i < 32; i += 8)
        tile[ty + i][tx] = Wi[(size_t)(kb + ty + i) * G_DIM + nb + tx];
    __syncthreads();
    #pragma unroll
    for (int i = 0; i < 32; i += 8)
        wiT[(size_t)(nb + ty + i) * E_DIM + kb + tx] = f2bf(tile[tx][ty + i]);
}

// ---------------------------------------------------------------------------
// Kernel F: fc_w (V x H fp32) -> bf16 copy.
// ---------------------------------------------------------------------------
__global__ __launch_bounds__(256) void fcwconv_kernel(const float* __restrict__ src,
                                                      unsigned short* __restrict__ dst)
{
    const size_t i = ((size_t)blockIdx.x * 256 + threadIdx.x) * 8;
    float4 a = *reinterpret_cast<const float4*>(src + i);
    float4 b = *reinterpret_cast<const float4*>(src + i + 4);
    ushortx8 o;
    o[0] = f2bf(a.x); o[1] = f2bf(a.y); o[2] = f2bf(a.z); o[3] = f2bf(a.w);
    o[4] = f2bf(b.x); o[5] = f2bf(b.y); o[6] = f2bf(b.z); o[7] = f2bf(b.w);
    *reinterpret_cast<ushortx8*>(dst + i) = o;
}

// ---------------------------------------------------------------------------
// Kernel A: xg = gather(embb, sent) @ wiT^T + bi + bh  (T x 4H) via bf16 MFMA.
// Tile 128(M) x 64(N), 4 waves, 8 MFMA per K-step, K=E=512. Same fragment
// layout as fc_kernel (validated round 5).
// ---------------------------------------------------------------------------
__global__ __launch_bounds__(256) void xg_mfma_kernel(const int* __restrict__ sent,
                                                      const unsigned short* __restrict__ embb,
                                                      const unsigned short* __restrict__ wiT,
                                                      const float* __restrict__ bi,
                                                      const float* __restrict__ bh,
                                                      unsigned short* __restrict__ xg)
{
    const int tid  = threadIdx.x;
    const int w    = tid >> 6;
    const int lane = tid & 63;
    const int n0 = blockIdx.x * 64;
    const int m0 = blockIdx.y * 128;
    const int lrow = lane & 15;
    const int lk   = (lane >> 4) * 8;

    const int r0 = sent[m0 + w * 32 + lrow];
    const int r1 = sent[m0 + w * 32 + 16 + lrow];

    floatx4 acc[2][4] = {};
    const unsigned short* a0p = embb + (size_t)r0 * E_DIM + lk;
    const unsigned short* a1p = embb + (size_t)r1 * E_DIM + lk;
    const unsigned short* b0p = wiT + (size_t)(n0 + lrow) * E_DIM + lk;

    for (int k0 = 0; k0 < E_DIM; k0 += 32) {
        shortx8 a0 = *reinterpret_cast<const shortx8*>(a0p + k0);
        shortx8 a1 = *reinterpret_cast<const shortx8*>(a1p + k0);
        shortx8 b0 = *reinterpret_cast<const shortx8*>(b0p + k0);
        shortx8 b1 = *reinterpret_cast<const shortx8*>(b0p + 16 * E_DIM + k0);
        shortx8 b2 = *reinterpret_cast<const shortx8*>(b0p + 32 * E_DIM + k0);
        shortx8 b3 = *reinterpret_cast<const shortx8*>(b0p + 48 * E_DIM + k0);
        acc[0][0] = __builtin_amdgcn_mfma_f32_16x16x32_bf16(a0, b0, acc[0][0], 0, 0, 0);
        acc[0][1] = __builtin_amdgcn_mfma_f32_16x16x32_bf16(a0, b1, acc[0][1], 0, 0, 0);
        acc[0][2] = __builtin_amdgcn_mfma_f32_16x16x32_bf16(a0, b2, acc[0][2], 0, 0, 0);
        acc[0][3] = __builtin_amdgcn_mfma_f32_16x16x32_bf16(a0, b3, acc[0][3], 0, 0, 0);
        acc[1][0] = __builtin_amdgcn_mfma_f32_16x16x32_bf16(a1, b0, acc[1][0], 0, 0, 0);
        acc[1][1] = __builtin_amdgcn_mfma_f32_16x16x32_bf16(a1, b1, acc[1][1], 0, 0, 0);
        acc[1][2] = __builtin_amdgcn_mfma_f32_16x16x32_bf16(a1, b2, acc[1][2], 0, 0, 0);
        acc[1][3] = __builtin_amdgcn_mfma_f32_16x16x32_bf16(a1, b3, acc[1][3], 0, 0, 0);
    }

    #pragma unroll
    for (int j = 0; j < 4; ++j) {
        const int c = n0 + j * 16 + lrow;
        const float bias = bi[c] + bh[c];
        #pragma unroll
        for (int i = 0; i < 2; ++i) {
            #pragma unroll
            for (int reg = 0; reg < 4; ++reg) {
                const int r = m0 + w * 32 + i * 16 + (lane >> 4) * 4 + reg;
                xg[(size_t)r * G_DIM + c] = f2bf(acc[i][j][reg] + bias);
            }
        }
    }
}

// ---------------------------------------------------------------------------
// Kernel B: persistent LSTM. 256 blocks x 256 threads; block b owns h-indices
// 4b..4b+3; wave w computes all 4 gate dots of h-index 4b+w -> lane 0 holds
// i,f,g,o. Handoff: hbuf[t][i] = (u16 tag=t+1)<<16 | bf16(h) -- ONE 4B
// device-scope store = data+signal. Consumers poll with coalesced dwordx4
// sc0 sc1 loads (poll IS the fetch). One barrier per step. Bounded spin.
// ---------------------------------------------------------------------------
__global__ __launch_bounds__(256) void lstm_kernel(const unsigned short* __restrict__ xg,
                                                   const unsigned short* __restrict__ whTp,
                                                   unsigned* __restrict__ hbuf,
                                                   int T)
{
    const int b    = blockIdx.x;
    const int tid  = threadIdx.x;
    const int w    = tid >> 6;
    const int lane = tid & 63;
    const int s    = b * 4;

    __shared__ float h_lds[H_DIM];

    float c_val = 0.0f;   // live in lane 0 of each wave

    for (int t = 0; t < T; ++t) {
        // prefetch this step's 4 xg values (lane 0 of each wave)
        float xr[4] = {0.f, 0.f, 0.f, 0.f};
        if (lane == 0) {
            #pragma unroll
            for (int q = 0; q < 4; ++q)
                xr[q] = bf2f(xg[(size_t)t * G_DIM + (q << 10) + s + w]);
        }

        // ---- poll+fetch h_{t-1}: thread owns 4 packed entries (16B)
        if (t) {
            const unsigned* pp = hbuf + (size_t)(t - 1) * H_DIM + tid * 4;
            const unsigned tg = (unsigned)t;
            uintx4 v;
            int guard = 0;
            bool ok;
            do {
                asm volatile("global_load_dwordx4 %0, %1, off sc0 sc1\n\t"
                             "s_waitcnt vmcnt(0)"
                             : "=&v"(v) : "v"(pp) : "memory");
                ok = ((v[0] >> 16) == tg) & ((v[1] >> 16) == tg)
                   & ((v[2] >> 16) == tg) & ((v[3] >> 16) == tg);
            } while (!ok && ++guard < 8192);
            floatx4 hv;
            hv[0] = __uint_as_float(v[0] << 16);
            hv[1] = __uint_as_float(v[1] << 16);
            hv[2] = __uint_as_float(v[2] << 16);
            hv[3] = __uint_as_float(v[3] << 16);
            *reinterpret_cast<floatx4*>(&h_lds[tid * 4]) = hv;
        } else {
            floatx4 z = {0.f, 0.f, 0.f, 0.f};
            *reinterpret_cast<floatx4*>(&h_lds[tid * 4]) = z;
        }
        __syncthreads();   // h_lds staged (sole barrier per step)

        // ---- h into registers (16/lane, c-interleaved: elem c*256+4*lane+e)
        float hreg[16];
        #pragma unroll
        for (int c = 0; c < 4; ++c) {
            floatx4 hv = *reinterpret_cast<const floatx4*>(&h_lds[c * 256 + lane * 4]);
            hreg[c * 4 + 0] = hv[0]; hreg[c * 4 + 1] = hv[1];
            hreg[c * 4 + 2] = hv[2]; hreg[c * 4 + 3] = hv[3];
        }

        // ---- wave w: 4 gate dots of h-index s+w (rows q*1024 + s + w)
        float sums[4];
        #pragma unroll
        for (int q = 0; q < 4; ++q) {
            const ushortx8* wp = reinterpret_cast<const ushortx8*>(
                whTp + ((size_t)((q << 10) + s + w)) * H_DIM + lane * 16);
            ushortx8 w0 = wp[0];
            ushortx8 w1 = wp[1];
            float sm = 0.f;
            #pragma unroll
            for (int e = 0; e < 8; ++e) sm += bf2f(w0[e]) * hreg[e];
            #pragma unroll
            for (int e = 0; e < 8; ++e) sm += bf2f(w1[e]) * hreg[8 + e];
            #pragma unroll
            for (int off = 32; off; off >>= 1) sm += __shfl_xor(sm, off, 64);
            sums[q] = sm;
        }

        // ---- lane 0: gates, state update, single 4B fused store
        if (lane == 0) {
            float ig = fast_sigmoid(sums[0] + xr[0]);
            float fg = fast_sigmoid(sums[1] + xr[1]);
            float gg = fast_tanh(sums[2] + xr[2]);
            float og = fast_sigmoid(sums[3] + xr[3]);
            c_val = fg * c_val + ig * gg;
            float h = og * fast_tanh(c_val);
            unsigned pk = ((unsigned)(t + 1) << 16) | (unsigned)f2bf(h);
            unsigned* sp = hbuf + (size_t)t * H_DIM + s + w;
            asm volatile("global_store_dword %0, %1, off sc0 sc1"
                         :: "v"(sp), "v"(pk) : "memory");
        }
        // no trailing barrier: next-step LDS writes are ordered behind the
        // poll, which requires this block's 4 stores, which follow all
        // waves' hreg reads.
    }
}

// ---------------------------------------------------------------------------
// Kernel H: hbuf packed {tag,bf16 h} -> hb bf16 (T x H).
// ---------------------------------------------------------------------------
__global__ __launch_bounds__(256) void hconv_kernel(const unsigned* __restrict__ hbuf,
                                                    unsigned short* __restrict__ hb)
{
    const size_t i = ((size_t)blockIdx.x * 256 + threadIdx.x) * 4;
    uintx4 v = *reinterpret_cast<const uintx4*>(hbuf + i);
    ushortx4 o;
    #pragma unroll
    for (int q = 0; q < 4; ++q)
        o[q] = (unsigned short)(v[q] & 0xFFFFu);
    *reinterpret_cast<ushortx4*>(hb + i) = o;
}

// ---------------------------------------------------------------------------
// Kernel C: logits = relu(hb @ fcwb^T + fc_b) -> d_out via bf16 MFMA.
// (unchanged from round 5 — validated)
// ---------------------------------------------------------------------------
__global__ __launch_bounds__(256) void fc_kernel(const unsigned short* __restrict__ hb,
                                                 const unsigned short* __restrict__ fcwb,
                                                 const float* __restrict__ fcb,
                                                 float* __restrict__ out)
{
    const int tid  = threadIdx.x;
    const int w    = tid >> 6;
    const int lane = tid & 63;
    const int n0 = blockIdx.x * 64;
    const int m0 = blockIdx.y * 128;
    const int lrow = lane & 15;
    const int lk   = (lane >> 4) * 8;

    floatx4 acc[2][4] = {};
    const unsigned short* a0p = hb + (size_t)(m0 + w * 32 + lrow) * H_DIM + lk;
    const unsigned short* a1p = a0p + 16 * H_DIM;
    const unsigned short* b0p = fcwb + (size_t)(n0 + lrow) * H_DIM + lk;

    for (int k0 = 0; k0 < H_DIM; k0 += 32) {
        shortx8 a0 = *reinterpret_cast<const shortx8*>(a0p + k0);
        shortx8 a1 = *reinterpret_cast<const shortx8*>(a1p + k0);
        shortx8 b0 = *reinterpret_cast<const shortx8*>(b0p + k0);
        shortx8 b1 = *reinterpret_cast<const shortx8*>(b0p + 16 * H_DIM + k0);
        shortx8 b2 = *reinterpret_cast<const shortx8*>(b0p + 32 * H_DIM + k0);
        shortx8 b3 = *reinterpret_cast<const shortx8*>(b0p + 48 * H_DIM + k0);
        acc[0][0] = __builtin_amdgcn_mfma_f32_16x16x32_bf16(a0, b0, acc[0][0], 0, 0, 0);
        acc[0][1] = __builtin_amdgcn_mfma_f32_16x16x32_bf16(a0, b1, acc[0][1], 0, 0, 0);
        acc[0][2] = __builtin_amdgcn_mfma_f32_16x16x32_bf16(a0, b2, acc[0][2], 0, 0, 0);
        acc[0][3] = __builtin_amdgcn_mfma_f32_16x16x32_bf16(a0, b3, acc[0][3], 0, 0, 0);
        acc[1][0] = __builtin_amdgcn_mfma_f32_16x16x32_bf16(a1, b0, acc[1][0], 0, 0, 0);
        acc[1][1] = __builtin_amdgcn_mfma_f32_16x16x32_bf16(a1, b1, acc[1][1], 0, 0, 0);
        acc[1][2] = __builtin_amdgcn_mfma_f32_16x16x32_bf16(a1, b2, acc[1][2], 0, 0, 0);
        acc[1][3] = __builtin_amdgcn_mfma_f32_16x16x32_bf16(a1, b3, acc[1][3], 0, 0, 0);
    }

    #pragma unroll
    for (int j = 0; j < 4; ++j) {
        const int c = n0 + j * 16 + lrow;
        const float bias = fcb[c];
        #pragma unroll
        for (int i = 0; i < 2; ++i) {
            #pragma unroll
            for (int reg = 0; reg < 4; ++reg) {
                const int r = m0 + w * 32 + i * 16 + (lane >> 4) * 4 + reg;
                out[(size_t)r * V_DIM + c] = fmaxf(acc[i][j][reg] + bias, 0.f);
            }
        }
    }
}

// ---------------------------------------------------------------------------
// Kernel D: in-place row log-softmax on d_out (online max/sum, 2 passes).
// ---------------------------------------------------------------------------
__global__ __launch_bounds__(256) void lsm_kernel(float* __restrict__ out)
{
    const int row = blockIdx.x;
    float* p = out + (size_t)row * V_DIM;
    const int tid = threadIdx.x;
    __shared__ float ms[256], ss[256];

    float m = -1e30f, sacc = 0.f;
    for (int i4 = tid; i4 < V_DIM / 4; i4 += 256) {
        float4 v = *reinterpret_cast<const float4*>(p + i4 * 4);
        float vm = fmaxf(fmaxf(v.x, v.y), fmaxf(v.z, v.w));
        if (vm > m) { sacc *= __expf(m - vm); m = vm; }
        sacc += __expf(v.x - m) + __expf(v.y - m) + __expf(v.z - m) + __expf(v.w - m);
    }
    ms[tid] = m; ss[tid] = sacc; __syncthreads();
    for (int sft = 128; sft; sft >>= 1) {
        if (tid < sft) {
            float m2 = ms[tid + sft], s2 = ss[tid + sft];
            float mm = fmaxf(ms[tid], m2);
            ss[tid] = ss[tid] * __expf(ms[tid] - mm) + s2 * __expf(m2 - mm);
            ms[tid] = mm;
        }
        __syncthreads();
    }
    const float L = ms[0] + logf(ss[0]);

    for (int i4 = tid; i4 < V_DIM / 4; i4 += 256) {
        float4 v = *reinterpret_cast<const float4*>(p + i4 * 4);
        v.x -= L; v.y -= L; v.z -= L; v.w -= L;
        *reinterpret_cast<float4*>(p + i4 * 4) = v;
    }
}

// ---------------------------------------------------------------------------
extern "C" void kernel_launch(void* const* d_in, const int* in_sizes, int n_in,
                              void* d_out, int out_size, void* d_ws, size_t ws_size,
                              hipStream_t stream)
{
    const int*   sent = (const int*)  d_in[0];
    const float* emb  = (const float*)d_in[1];
    const float* Wi   = (const float*)d_in[2];
    const float* Wh   = (const float*)d_in[3];
    const float* bi   = (const float*)d_in[4];
    const float* bh   = (const float*)d_in[5];
    const float* fcw  = (const float*)d_in[6];
    const float* fcb  = (const float*)d_in[7];
    float* out = (float*)d_out;

    uint8_t* ws = (uint8_t*)d_ws;
    size_t off = 0;
    unsigned*       hbuf = (unsigned*)(ws + off);       off += (size_t)T_LEN * H_DIM * 4;  //  8.4 MB
    unsigned short* xg   = (unsigned short*)(ws + off); off += (size_t)T_LEN * G_DIM * 2;  // 16.8 MB
    unsigned short* whTp = (unsigned short*)(ws + off); off += (size_t)G_DIM * H_DIM * 2;  //  8.4 MB
    unsigned short* hb   = (unsigned short*)(ws + off); off += (size_t)T_LEN * H_DIM * 2;  //  4.2 MB
    // overlay region: embb+wiT live only until xg_mfma; fcwb (larger) reuses it
    uint8_t* R = ws + off;                              // 65.5 MB region
    unsigned short* fcwb = (unsigned short*)R;
    unsigned short* embb = (unsigned short*)R;                                   // 32.8 MB
    unsigned short* wiT  = (unsigned short*)(R + (size_t)V_DIM * E_DIM * 2);     //  4.2 MB

    hipMemsetAsync(hbuf, 0, (size_t)T_LEN * H_DIM * 4, stream);
    embconv_kernel<<<(int)(((size_t)V_DIM * E_DIM / 8) / 256), 256, 0, stream>>>(emb, embb);
    wiconv_kernel<<<dim3(G_DIM / 32, E_DIM / 32), 256, 0, stream>>>(Wi, wiT);
    prep_kernel<<<G_DIM / 16, 256, 0, stream>>>(Wh, whTp);
    xg_mfma_kernel<<<dim3(G_DIM / 64, T_LEN / 128), 256, 0, stream>>>(sent, embb, wiT, bi, bh, xg);
    fcwconv_kernel<<<(int)(((size_t)V_DIM * H_DIM / 8) / 256), 256, 0, stream>>>(fcw, fcwb);  // overwrites embb/wiT (dead)
    lstm_kernel<<<LSTM_NB, 256, 0, stream>>>(xg, whTp, hbuf, T_LEN);
    hconv_kernel<<<(int)(((size_t)T_LEN * H_DIM / 4) / 256), 256, 0, stream>>>(hbuf, hb);
    fc_kernel<<<dim3(V_DIM / 64, T_LEN / 128), 256, 0, stream>>>(hb, fcwb, fcb, out);
    lsm_kernel<<<T_LEN, 256, 0, stream>>>(out);
}

// Round 7
// 5524.805 us; speedup vs baseline: 3.8501x; 1.0490x over previous
//
#include <hip/hip_runtime.h>
#include <hip/hip_bf16.h>
#include <cmath>

#define T_LEN 2048
#define E_DIM 512
#define H_DIM 1024
#define G_DIM 4096   // 4*H
#define V_DIM 32000
#define LSTM_NB 256  // persistent blocks (1 per CU)
#define NREP 8       // handoff replicas (spread poll load over 8x lines)
#define RING 4       // handoff ring depth (skew between blocks is <= 1 step)

typedef unsigned short ushortx8 __attribute__((ext_vector_type(8)));
typedef unsigned short ushortx4 __attribute__((ext_vector_type(4)));
typedef short shortx8 __attribute__((ext_vector_type(8)));
typedef float floatx4 __attribute__((ext_vector_type(4)));
typedef unsigned uintx4 __attribute__((ext_vector_type(4)));

__device__ __forceinline__ float bf2f(unsigned short u) {
    return __uint_as_float(((unsigned)u) << 16);
}
__device__ __forceinline__ unsigned short f2bf(float f) {
    __hip_bfloat16 b = __float2bfloat16(f);
    return *reinterpret_cast<unsigned short*>(&b);
}
__device__ __forceinline__ float fast_sigmoid(float x) {
    return 1.f / (1.f + __expf(-x));
}
__device__ __forceinline__ float fast_tanh(float x) {
    return 1.f - 2.f / (__expf(2.f * x) + 1.f);
}

// ---------------------------------------------------------------------------
// Kernel P: Wh (H x 4H fp32) -> whTp (4H x H bf16), lane-permuted per row:
//   source h-index i stored at pos = ((i&255)>>2)*16 + (i>>8)*4 + (i&3)
// ---------------------------------------------------------------------------
__global__ __launch_bounds__(256) void prep_kernel(const float* __restrict__ Wh,
                                                   unsigned short* __restrict__ whTp)
{
    const int c0  = blockIdx.x * 16;
    const int tid = threadIdx.x;
    const int cc  = tid & 15;
    const int kk  = tid >> 4;
    const int col = c0 + cc;
    unsigned short* dst = whTp + (size_t)col * H_DIM;
    #pragma unroll 4
    for (int r = 0; r < 64; ++r) {
        const int i = r * 16 + kk;
        float v = Wh[(size_t)i * G_DIM + col];
        const int pos = ((i & 255) >> 2) * 16 + (i >> 8) * 4 + (i & 3);
        dst[pos] = f2bf(v);
    }
}

// ---------------------------------------------------------------------------
// Kernel E: emb (V x E fp32) -> bf16 copy.
// ---------------------------------------------------------------------------
__global__ __launch_bounds__(256) void embconv_kernel(const float* __restrict__ src,
                                                      unsigned short* __restrict__ dst)
{
    const size_t i = ((size_t)blockIdx.x * 256 + threadIdx.x) * 8;
    float4 a = *reinterpret_cast<const float4*>(src + i);
    float4 b = *reinterpret_cast<const float4*>(src + i + 4);
    ushortx8 o;
    o[0] = f2bf(a.x); o[1] = f2bf(a.y); o[2] = f2bf(a.z); o[3] = f2bf(a.w);
    o[4] = f2bf(b.x); o[5] = f2bf(b.y); o[6] = f2bf(b.z); o[7] = f2bf(b.w);
    *reinterpret_cast<ushortx8*>(dst + i) = o;
}

// ---------------------------------------------------------------------------
// Kernel W: Wi (E x 4H fp32) -> wiT (4H x E bf16) transpose+convert.
// ---------------------------------------------------------------------------
__global__ __launch_bounds__(256) void wiconv_kernel(const float* __restrict__ Wi,
                                                     unsigned short* __restrict__ wiT)
{
    __shared__ float tile[32][33];
    const int nb = blockIdx.x * 32;
    const int kb = blockIdx.y * 32;
    const int tx = threadIdx.x & 31;
    const int ty = threadIdx.x >> 5;  // 0..7
    #pragma unroll
    for (int i = 0; i < 32; i += 8)
        tile[ty + i][tx] = Wi[(size_t)(kb + ty + i) * G_DIM + nb + tx];
    __syncthreads();
    #pragma unroll
    for (int i = 0; i < 32; i += 8)
        wiT[(size_t)(nb + ty + i) * E_DIM + kb + tx] = f2bf(tile[tx][ty + i]);
}

// ---------------------------------------------------------------------------
// Kernel F: fc_w (V x H fp32) -> bf16 copy.
// ---------------------------------------------------------------------------
__global__ __launch_bounds__(256) void fcwconv_kernel(const float* __restrict__ src,
                                                      unsigned short* __restrict__ dst)
{
    const size_t i = ((size_t)blockIdx.x * 256 + threadIdx.x) * 8;
    float4 a = *reinterpret_cast<const float4*>(src + i);
    float4 b = *reinterpret_cast<const float4*>(src + i + 4);
    ushortx8 o;
    o[0] = f2bf(a.x); o[1] = f2bf(a.y); o[2] = f2bf(a.z); o[3] = f2bf(a.w);
    o[4] = f2bf(b.x); o[5] = f2bf(b.y); o[6] = f2bf(b.z); o[7] = f2bf(b.w);
    *reinterpret_cast<ushortx8*>(dst + i) = o;
}

// ---------------------------------------------------------------------------
// Kernel A: xg = gather(embb, sent) @ wiT^T + bi + bh  via bf16 MFMA.
// Output layout GATE-CONTIGUOUS: xg2[t][hidx][gate] (T x 1024 x 4 bf16),
// so the LSTM's lane0 fetches all 4 gate biases of its h-index in ONE 8B load.
// ---------------------------------------------------------------------------
__global__ __launch_bounds__(256) void xg_mfma_kernel(const int* __restrict__ sent,
                                                      const unsigned short* __restrict__ embb,
                                                      const unsigned short* __restrict__ wiT,
                                                      const float* __restrict__ bi,
                                                      const float* __restrict__ bh,
                                                      unsigned short* __restrict__ xg2)
{
    const int tid  = threadIdx.x;
    const int w    = tid >> 6;
    const int lane = tid & 63;
    const int n0 = blockIdx.x * 64;
    const int m0 = blockIdx.y * 128;
    const int lrow = lane & 15;
    const int lk   = (lane >> 4) * 8;

    const int r0 = sent[m0 + w * 32 + lrow];
    const int r1 = sent[m0 + w * 32 + 16 + lrow];

    floatx4 acc[2][4] = {};
    const unsigned short* a0p = embb + (size_t)r0 * E_DIM + lk;
    const unsigned short* a1p = embb + (size_t)r1 * E_DIM + lk;
    const unsigned short* b0p = wiT + (size_t)(n0 + lrow) * E_DIM + lk;

    for (int k0 = 0; k0 < E_DIM; k0 += 32) {
        shortx8 a0 = *reinterpret_cast<const shortx8*>(a0p + k0);
        shortx8 a1 = *reinterpret_cast<const shortx8*>(a1p + k0);
        shortx8 b0 = *reinterpret_cast<const shortx8*>(b0p + k0);
        shortx8 b1 = *reinterpret_cast<const shortx8*>(b0p + 16 * E_DIM + k0);
        shortx8 b2 = *reinterpret_cast<const shortx8*>(b0p + 32 * E_DIM + k0);
        shortx8 b3 = *reinterpret_cast<const shortx8*>(b0p + 48 * E_DIM + k0);
        acc[0][0] = __builtin_amdgcn_mfma_f32_16x16x32_bf16(a0, b0, acc[0][0], 0, 0, 0);
        acc[0][1] = __builtin_amdgcn_mfma_f32_16x16x32_bf16(a0, b1, acc[0][1], 0, 0, 0);
        acc[0][2] = __builtin_amdgcn_mfma_f32_16x16x32_bf16(a0, b2, acc[0][2], 0, 0, 0);
        acc[0][3] = __builtin_amdgcn_mfma_f32_16x16x32_bf16(a0, b3, acc[0][3], 0, 0, 0);
        acc[1][0] = __builtin_amdgcn_mfma_f32_16x16x32_bf16(a1, b0, acc[1][0], 0, 0, 0);
        acc[1][1] = __builtin_amdgcn_mfma_f32_16x16x32_bf16(a1, b1, acc[1][1], 0, 0, 0);
        acc[1][2] = __builtin_amdgcn_mfma_f32_16x16x32_bf16(a1, b2, acc[1][2], 0, 0, 0);
        acc[1][3] = __builtin_amdgcn_mfma_f32_16x16x32_bf16(a1, b3, acc[1][3], 0, 0, 0);
    }

    #pragma unroll
    for (int j = 0; j < 4; ++j) {
        const int c = n0 + j * 16 + lrow;     // global gate-col in [0,4096)
        const int hidx = c & 1023;
        const int gate = c >> 10;
        const float bias = bi[c] + bh[c];
        #pragma unroll
        for (int i = 0; i < 2; ++i) {
            #pragma unroll
            for (int reg = 0; reg < 4; ++reg) {
                const int r = m0 + w * 32 + i * 16 + (lane >> 4) * 4 + reg;
                xg2[(size_t)r * G_DIM + hidx * 4 + gate] = f2bf(acc[i][j][reg] + bias);
            }
        }
    }
}

// ---------------------------------------------------------------------------
// Kernel B: persistent LSTM. 256 blocks x 256 threads; block b owns h-indices
// 4b..4b+3; wave w computes the 4 gate dots of h-index 4b+w (lane 0 holds
// i,f,g,o). Handoff: ring[(t&3)][rep][i] = (tag=t+1)<<16 | bf16(h), written
// to ALL NREP=8 replicas (8 fused dword stores = data+signal). Consumer block
// b polls ONLY replica b&7 -> per-line reader count drops 8x (hot-line
// decongestion). Exact tag==t check makes ring reuse safe (block skew <= 1).
// Producers also write hb (plain cached bf16) for the fc kernel.
// ---------------------------------------------------------------------------
__global__ __launch_bounds__(256) void lstm_kernel(const unsigned short* __restrict__ xg2,
                                                   const unsigned short* __restrict__ whTp,
                                                   unsigned* __restrict__ ring,
                                                   unsigned short* __restrict__ hb,
                                                   int T)
{
    const int b    = blockIdx.x;
    const int tid  = threadIdx.x;
    const int w    = tid >> 6;
    const int lane = tid & 63;
    const int s    = b * 4;
    const int rep  = b & (NREP - 1);

    __shared__ float h_lds[H_DIM];

    float c_val = 0.0f;   // live in lane 0 of each wave

    for (int t = 0; t < T; ++t) {
        // prefetch this step's 4 gate biases for h-index s+w (ONE 8B load)
        float xr[4] = {0.f, 0.f, 0.f, 0.f};
        if (lane == 0) {
            ushortx4 xv = *reinterpret_cast<const ushortx4*>(
                xg2 + (size_t)t * G_DIM + (size_t)(s + w) * 4);
            #pragma unroll
            for (int q = 0; q < 4; ++q) xr[q] = bf2f(xv[q]);
        }

        // ---- poll+fetch h_{t-1} from replica `rep` of ring slot (t-1)&3
        if (t) {
            const unsigned* pp = ring + ((t - 1) & (RING - 1)) * (NREP * H_DIM)
                                      + rep * H_DIM + tid * 4;
            const unsigned tg = (unsigned)t;
            uintx4 v;
            int guard = 0;
            bool ok;
            do {
                asm volatile("global_load_dwordx4 %0, %1, off sc0 sc1\n\t"
                             "s_waitcnt vmcnt(0)"
                             : "=&v"(v) : "v"(pp) : "memory");
                ok = ((v[0] >> 16) == tg) & ((v[1] >> 16) == tg)
                   & ((v[2] >> 16) == tg) & ((v[3] >> 16) == tg);
            } while (!ok && ++guard < 8192);
            floatx4 hv;
            hv[0] = __uint_as_float(v[0] << 16);
            hv[1] = __uint_as_float(v[1] << 16);
            hv[2] = __uint_as_float(v[2] << 16);
            hv[3] = __uint_as_float(v[3] << 16);
            *reinterpret_cast<floatx4*>(&h_lds[tid * 4]) = hv;
        } else {
            floatx4 z = {0.f, 0.f, 0.f, 0.f};
            *reinterpret_cast<floatx4*>(&h_lds[tid * 4]) = z;
        }
        __syncthreads();   // h_lds staged (sole barrier per step)

        // ---- h into registers (16/lane, c-interleaved: elem c*256+4*lane+e)
        float hreg[16];
        #pragma unroll
        for (int c = 0; c < 4; ++c) {
            floatx4 hv = *reinterpret_cast<const floatx4*>(&h_lds[c * 256 + lane * 4]);
            hreg[c * 4 + 0] = hv[0]; hreg[c * 4 + 1] = hv[1];
            hreg[c * 4 + 2] = hv[2]; hreg[c * 4 + 3] = hv[3];
        }

        // ---- wave w: 4 gate dots of h-index s+w (rows q*1024 + s + w)
        float sums[4];
        #pragma unroll
        for (int q = 0; q < 4; ++q) {
            const ushortx8* wp = reinterpret_cast<const ushortx8*>(
                whTp + ((size_t)((q << 10) + s + w)) * H_DIM + lane * 16);
            ushortx8 w0 = wp[0];
            ushortx8 w1 = wp[1];
            float sm = 0.f;
            #pragma unroll
            for (int e = 0; e < 8; ++e) sm += bf2f(w0[e]) * hreg[e];
            #pragma unroll
            for (int e = 0; e < 8; ++e) sm += bf2f(w1[e]) * hreg[8 + e];
            #pragma unroll
            for (int off = 32; off; off >>= 1) sm += __shfl_xor(sm, off, 64);
            sums[q] = sm;
        }

        // ---- lane 0: gates, state update, 8 replica stores + plain hb store
        if (lane == 0) {
            float ig = fast_sigmoid(sums[0] + xr[0]);
            float fg = fast_sigmoid(sums[1] + xr[1]);
            float gg = fast_tanh(sums[2] + xr[2]);
            float og = fast_sigmoid(sums[3] + xr[3]);
            c_val = fg * c_val + ig * gg;
            float h = og * fast_tanh(c_val);
            const unsigned short hbf = f2bf(h);
            const unsigned pk = ((unsigned)(t + 1) << 16) | (unsigned)hbf;
            unsigned* base = ring + (t & (RING - 1)) * (NREP * H_DIM) + s + w;
            #pragma unroll
            for (int r = 0; r < NREP; ++r) {
                unsigned* sp = base + r * H_DIM;
                asm volatile("global_store_dword %0, %1, off sc0 sc1"
                             :: "v"(sp), "v"(pk) : "memory");
            }
            hb[(size_t)t * H_DIM + s + w] = hbf;   // cached; visible to fc at kernel end
        }
        // no trailing barrier: next-step LDS writes are ordered behind the
        // poll, which requires this block's stores, which follow hreg reads.
    }
}

// ---------------------------------------------------------------------------
// Kernel C: logits = relu(hb @ fcwb^T + fc_b) -> d_out via bf16 MFMA.
// (unchanged — validated)
// ---------------------------------------------------------------------------
__global__ __launch_bounds__(256) void fc_kernel(const unsigned short* __restrict__ hb,
                                                 const unsigned short* __restrict__ fcwb,
                                                 const float* __restrict__ fcb,
                                                 float* __restrict__ out)
{
    const int tid  = threadIdx.x;
    const int w    = tid >> 6;
    const int lane = tid & 63;
    const int n0 = blockIdx.x * 64;
    const int m0 = blockIdx.y * 128;
    const int lrow = lane & 15;
    const int lk   = (lane >> 4) * 8;

    floatx4 acc[2][4] = {};
    const unsigned short* a0p = hb + (size_t)(m0 + w * 32 + lrow) * H_DIM + lk;
    const unsigned short* a1p = a0p + 16 * H_DIM;
    const unsigned short* b0p = fcwb + (size_t)(n0 + lrow) * H_DIM + lk;

    for (int k0 = 0; k0 < H_DIM; k0 += 32) {
        shortx8 a0 = *reinterpret_cast<const shortx8*>(a0p + k0);
        shortx8 a1 = *reinterpret_cast<const shortx8*>(a1p + k0);
        shortx8 b0 = *reinterpret_cast<const shortx8*>(b0p + k0);
        shortx8 b1 = *reinterpret_cast<const shortx8*>(b0p + 16 * H_DIM + k0);
        shortx8 b2 = *reinterpret_cast<const shortx8*>(b0p + 32 * H_DIM + k0);
        shortx8 b3 = *reinterpret_cast<const shortx8*>(b0p + 48 * H_DIM + k0);
        acc[0][0] = __builtin_amdgcn_mfma_f32_16x16x32_bf16(a0, b0, acc[0][0], 0, 0, 0);
        acc[0][1] = __builtin_amdgcn_mfma_f32_16x16x32_bf16(a0, b1, acc[0][1], 0, 0, 0);
        acc[0][2] = __builtin_amdgcn_mfma_f32_16x16x32_bf16(a0, b2, acc[0][2], 0, 0, 0);
        acc[0][3] = __builtin_amdgcn_mfma_f32_16x16x32_bf16(a0, b3, acc[0][3], 0, 0, 0);
        acc[1][0] = __builtin_amdgcn_mfma_f32_16x16x32_bf16(a1, b0, acc[1][0], 0, 0, 0);
        acc[1][1] = __builtin_amdgcn_mfma_f32_16x16x32_bf16(a1, b1, acc[1][1], 0, 0, 0);
        acc[1][2] = __builtin_amdgcn_mfma_f32_16x16x32_bf16(a1, b2, acc[1][2], 0, 0, 0);
        acc[1][3] = __builtin_amdgcn_mfma_f32_16x16x32_bf16(a1, b3, acc[1][3], 0, 0, 0);
    }

    #pragma unroll
    for (int j = 0; j < 4; ++j) {
        const int c = n0 + j * 16 + lrow;
        const float bias = fcb[c];
        #pragma unroll
        for (int i = 0; i < 2; ++i) {
            #pragma unroll
            for (int reg = 0; reg < 4; ++reg) {
                const int r = m0 + w * 32 + i * 16 + (lane >> 4) * 4 + reg;
                out[(size_t)r * V_DIM + c] = fmaxf(acc[i][j][reg] + bias, 0.f);
            }
        }
    }
}

// ---------------------------------------------------------------------------
// Kernel D: in-place row log-softmax on d_out (online max/sum, 2 passes).
// ---------------------------------------------------------------------------
__global__ __launch_bounds__(256) void lsm_kernel(float* __restrict__ out)
{
    const int row = blockIdx.x;
    float* p = out + (size_t)row * V_DIM;
    const int tid = threadIdx.x;
    __shared__ float ms[256], ss[256];

    float m = -1e30f, sacc = 0.f;
    for (int i4 = tid; i4 < V_DIM / 4; i4 += 256) {
        float4 v = *reinterpret_cast<const float4*>(p + i4 * 4);
        float vm = fmaxf(fmaxf(v.x, v.y), fmaxf(v.z, v.w));
        if (vm > m) { sacc *= __expf(m - vm); m = vm; }
        sacc += __expf(v.x - m) + __expf(v.y - m) + __expf(v.z - m) + __expf(v.w - m);
    }
    ms[tid] = m; ss[tid] = sacc; __syncthreads();
    for (int sft = 128; sft; sft >>= 1) {
        if (tid < sft) {
            float m2 = ms[tid + sft], s2 = ss[tid + sft];
            float mm = fmaxf(ms[tid], m2);
            ss[tid] = ss[tid] * __expf(ms[tid] - mm) + s2 * __expf(m2 - mm);
            ms[tid] = mm;
        }
        __syncthreads();
    }
    const float L = ms[0] + logf(ss[0]);

    for (int i4 = tid; i4 < V_DIM / 4; i4 += 256) {
        float4 v = *reinterpret_cast<const float4*>(p + i4 * 4);
        v.x -= L; v.y -= L; v.z -= L; v.w -= L;
        *reinterpret_cast<float4*>(p + i4 * 4) = v;
    }
}

// ---------------------------------------------------------------------------
extern "C" void kernel_launch(void* const* d_in, const int* in_sizes, int n_in,
                              void* d_out, int out_size, void* d_ws, size_t ws_size,
                              hipStream_t stream)
{
    const int*   sent = (const int*)  d_in[0];
    const float* emb  = (const float*)d_in[1];
    const float* Wi   = (const float*)d_in[2];
    const float* Wh   = (const float*)d_in[3];
    const float* bi   = (const float*)d_in[4];
    const float* bh   = (const float*)d_in[5];
    const float* fcw  = (const float*)d_in[6];
    const float* fcb  = (const float*)d_in[7];
    float* out = (float*)d_out;

    uint8_t* ws = (uint8_t*)d_ws;
    size_t off = 0;
    unsigned*       ring = (unsigned*)(ws + off);       off += (size_t)RING * NREP * H_DIM * 4; // 128 KiB
    unsigned short* xg2  = (unsigned short*)(ws + off); off += (size_t)T_LEN * G_DIM * 2;  // 16.8 MB
    unsigned short* whTp = (unsigned short*)(ws + off); off += (size_t)G_DIM * H_DIM * 2;  //  8.4 MB
    unsigned short* hb   = (unsigned short*)(ws + off); off += (size_t)T_LEN * H_DIM * 2;  //  4.2 MB
    // overlay region: embb+wiT live only until xg_mfma; fcwb (larger) reuses it
    uint8_t* R = ws + off;
    unsigned short* fcwb = (unsigned short*)R;                                   // 65.5 MB
    unsigned short* embb = (unsigned short*)R;                                   // 32.8 MB
    unsigned short* wiT  = (unsigned short*)(R + (size_t)V_DIM * E_DIM * 2);     //  4.2 MB

    hipMemsetAsync(ring, 0, (size_t)RING * NREP * H_DIM * 4, stream);
    embconv_kernel<<<(int)(((size_t)V_DIM * E_DIM / 8) / 256), 256, 0, stream>>>(emb, embb);
    wiconv_kernel<<<dim3(G_DIM / 32, E_DIM / 32), 256, 0, stream>>>(Wi, wiT);
    prep_kernel<<<G_DIM / 16, 256, 0, stream>>>(Wh, whTp);
    xg_mfma_kernel<<<dim3(G_DIM / 64, T_LEN / 128), 256, 0, stream>>>(sent, embb, wiT, bi, bh, xg2);
    fcwconv_kernel<<<(int)(((size_t)V_DIM * H_DIM / 8) / 256), 256, 0, stream>>>(fcw, fcwb);  // overwrites embb/wiT (dead)
    lstm_kernel<<<LSTM_NB, 256, 0, stream>>>(xg2, whTp, ring, hb, T_LEN);
    fc_kernel<<<dim3(V_DIM / 64, T_LEN / 128), 256, 0, stream>>>(hb, fcwb, fcb, out);
    lsm_kernel<<<T_LEN, 256, 0, stream>>>(out);
}